// Round 7
// baseline (1859.778 us; speedup 1.0000x reference)
//
#include <hip/hip_runtime.h>
#include <hip/hip_fp16.h>

typedef __bf16 bf16;
typedef bf16 bf16x8 __attribute__((ext_vector_type(8)));
typedef float f32x4 __attribute__((ext_vector_type(4)));

#define LD64  80   // padded LDS row stride (elems) for 64-wide tiles
#define LD128 144  // padded LDS row stride for 128-wide tiles

static __device__ __forceinline__ f32x4 mfma16(bf16x8 a, bf16x8 b, f32x4 c) {
    return __builtin_amdgcn_mfma_f32_16x16x32_bf16(a, b, c, 0, 0, 0);
}

static __device__ __forceinline__ bf16x8 cvt8(float4 a, float4 b) {
    bf16x8 v;
    v[0] = (bf16)a.x; v[1] = (bf16)a.y; v[2] = (bf16)a.z; v[3] = (bf16)a.w;
    v[4] = (bf16)b.x; v[5] = (bf16)b.y; v[6] = (bf16)b.z; v[7] = (bf16)b.w;
    return v;
}

static __device__ __forceinline__ uint32_t pack_bf16(float lo, float hi) {
    bf16 a = (bf16)lo, b = (bf16)hi;
    uint16_t ua = *(uint16_t*)&a, ub = *(uint16_t*)&b;
    return ((uint32_t)ub << 16) | (uint32_t)ua;
}

// --- helpers for the fallback (f16 agg) path ---
static __device__ __forceinline__ uint32_t pack_f16(float lo, float hi) {
    __half hl = __float2half_rn(lo), hh = __float2half_rn(hi);
    uint16_t a = *(uint16_t*)&hl, b = *(uint16_t*)&hh;
    return ((uint32_t)b << 16) | (uint32_t)a;
}
static __device__ __forceinline__ void atomic_pk_f16(__half* addr, uint32_t v) {
    asm volatile("global_atomic_pk_add_f16 %0, %1, off" :: "v"(addr), "v"(v) : "memory");
}
static __device__ __forceinline__ float h2f_lo(uint32_t u) {
    uint16_t s = (uint16_t)u; __half h = *(__half*)&s; return __half2float(h);
}
static __device__ __forceinline__ float h2f_hi(uint32_t u) {
    uint16_t s = (uint16_t)(u >> 16); __half h = *(__half*)&s; return __half2float(h);
}

// ===========================================================================
// FRONT: blocks [0,HB) = histogram of rel1+rel2 dests.
//        blocks [HB, HB+PT) = prep3: per node tile, from one emb read produce
//          P0[n]=emb@W1m[0:64,:]+b1m, P1[n]=emb@W1m[64:,:]  (bf16)
//          aggu[n]=MLP1(emb[n])  (UNscaled rel1 message; cnt1 applied later)
// ===========================================================================
__global__ __launch_bounds__(256) void front_kernel(
    const int* __restrict__ r1, const int* __restrict__ r2,
    unsigned* __restrict__ cnt1, unsigned* __restrict__ cnt2,
    int M1, int M2x2, int HB,
    const float* __restrict__ emb,
    const float* __restrict__ mW1, const float* __restrict__ mb1,   // 128x128,128
    const float* __restrict__ r1W1, const float* __restrict__ r1b1, // 64x64,64
    const float* __restrict__ r1W2, const float* __restrict__ r1b2,
    bf16* __restrict__ P0, bf16* __restrict__ P1,
    float* __restrict__ aggu, int N, int PT)
{
    __shared__ bf16 sG[64 * LD64];
    __shared__ bf16 sH[64 * LD64];
    __shared__ bf16 sW1t[64 * LD64];
    __shared__ bf16 sW2t[64 * LD64];
    __shared__ float sB1[64], sB2[64];

    const int t = threadIdx.x;

    if ((int)blockIdx.x < HB) {   // ---- histogram ----
        int i = blockIdx.x * 256 + t;
        const int T = HB * 256;
        const int tot = M1 + M2x2;
        for (; i < tot; i += T) {
            if (i < M1) atomicAdd(&cnt1[r1[i]], 1u);
            else        atomicAdd(&cnt2[r2[i - M1]], 1u);
        }
        return;
    }

    // ---- prep3 ----
    const int bid = blockIdx.x - HB;
    const int G = gridDim.x - HB;
    const int wave = t >> 6, lane = t & 63;
    const int l15 = lane & 15, quad = lane >> 4;
    const int r = t >> 2, p = t & 3;

    for (int i = t; i < 64 * 64; i += 256) {
        int k = i >> 6, n = i & 63;
        sW1t[n * LD64 + k] = (bf16)r1W1[i];
        sW2t[n * LD64 + k] = (bf16)r1W2[i];
    }
    if (t < 64) { sB1[t] = r1b1[t]; sB2[t] = r1b2[t]; }

    // msg W1 fragments in registers: n-tiles {2*wave, 2*wave+1}
    bf16x8 wf0[2][2], wf1[2][2];
    float biasv[2];
    #pragma unroll
    for (int j = 0; j < 2; ++j) {
        const int n = (wave * 2 + j) * 16 + l15;
        biasv[j] = mb1[n];
        #pragma unroll
        for (int kt = 0; kt < 2; ++kt) {
            bf16x8 f0, f1;
            #pragma unroll
            for (int e = 0; e < 8; ++e) {
                int k = kt * 32 + quad * 8 + e;
                f0[e] = (bf16)mW1[k * 128 + n];
                f1[e] = (bf16)mW1[(64 + k) * 128 + n];
            }
            wf0[j][kt] = f0;
            wf1[j][kt] = f1;
        }
    }

    for (int tile = bid; tile < PT; tile += G) {
        __syncthreads();
        const int base = tile * 64;
        const int R = base + r;
        if (R < N) {
            const float4* src = (const float4*)(emb + (size_t)R * 64 + p * 16);
            float4 v0 = src[0], v1 = src[1], v2 = src[2], v3 = src[3];
            *(bf16x8*)&sG[r * LD64 + p * 16 + 0] = cvt8(v0, v1);
            *(bf16x8*)&sG[r * LD64 + p * 16 + 8] = cvt8(v2, v3);
        }
        __syncthreads();

        // --- P-part ---
        f32x4 a0[4][2], a1[4][2];
        #pragma unroll
        for (int mt = 0; mt < 4; ++mt)
            #pragma unroll
            for (int j = 0; j < 2; ++j) {
                a0[mt][j] = (f32x4){0.f, 0.f, 0.f, 0.f};
                a1[mt][j] = (f32x4){0.f, 0.f, 0.f, 0.f};
            }
        #pragma unroll
        for (int mt = 0; mt < 4; ++mt)
            #pragma unroll
            for (int kt = 0; kt < 2; ++kt) {
                bf16x8 a = *(const bf16x8*)&sG[(mt * 16 + l15) * LD64 + kt * 32 + quad * 8];
                #pragma unroll
                for (int j = 0; j < 2; ++j) {
                    a0[mt][j] = mfma16(a, wf0[j][kt], a0[mt][j]);
                    a1[mt][j] = mfma16(a, wf1[j][kt], a1[mt][j]);
                }
            }
        #pragma unroll
        for (int mt = 0; mt < 4; ++mt)
            #pragma unroll
            for (int j = 0; j < 2; ++j) {
                const int colb = (wave * 2 + j) * 16 + (l15 & ~1);
                const int odd = l15 & 1;
                #pragma unroll
                for (int rr = 0; rr < 4; ++rr) {
                    float v = a0[mt][j][rr] + biasv[j];
                    float o = __shfl_xor(v, 1);
                    float w = a1[mt][j][rr];
                    float ow = __shfl_xor(w, 1);
                    if ((rr >> 1) == odd) {
                        int node = base + mt * 16 + quad * 4 + rr;
                        if (node < N) {
                            *(uint32_t*)&P0[(size_t)node * 128 + colb] =
                                odd ? pack_bf16(o, v) : pack_bf16(v, o);
                            *(uint32_t*)&P1[(size_t)node * 128 + colb] =
                                odd ? pack_bf16(ow, w) : pack_bf16(w, ow);
                        }
                    }
                }
            }

        // --- rel1 MLP (unscaled) ---
        f32x4 acc[4];
        #pragma unroll
        for (int nt = 0; nt < 4; ++nt) acc[nt] = (f32x4){0.f, 0.f, 0.f, 0.f};
        #pragma unroll
        for (int kt = 0; kt < 2; ++kt) {
            bf16x8 a = *(const bf16x8*)&sG[(wave * 16 + l15) * LD64 + kt * 32 + quad * 8];
            #pragma unroll
            for (int nt = 0; nt < 4; ++nt) {
                bf16x8 bfr = *(const bf16x8*)&sW1t[(nt * 16 + l15) * LD64 + kt * 32 + quad * 8];
                acc[nt] = mfma16(a, bfr, acc[nt]);
            }
        }
        #pragma unroll
        for (int nt = 0; nt < 4; ++nt) {
            float bias = sB1[nt * 16 + l15];
            #pragma unroll
            for (int rr = 0; rr < 4; ++rr) {
                float v = acc[nt][rr] + bias;
                v = v > 0.f ? v : 0.f;
                sH[(wave * 16 + quad * 4 + rr) * LD64 + nt * 16 + l15] = (bf16)v;
            }
        }
        __syncthreads();

        f32x4 acc2[4];
        #pragma unroll
        for (int nt = 0; nt < 4; ++nt) acc2[nt] = (f32x4){0.f, 0.f, 0.f, 0.f};
        #pragma unroll
        for (int kt = 0; kt < 2; ++kt) {
            bf16x8 a = *(const bf16x8*)&sH[(wave * 16 + l15) * LD64 + kt * 32 + quad * 8];
            #pragma unroll
            for (int nt = 0; nt < 4; ++nt) {
                bf16x8 bfr = *(const bf16x8*)&sW2t[(nt * 16 + l15) * LD64 + kt * 32 + quad * 8];
                acc2[nt] = mfma16(a, bfr, acc2[nt]);
            }
        }
        #pragma unroll
        for (int nt = 0; nt < 4; ++nt) {
            float bias = sB2[nt * 16 + l15];
            #pragma unroll
            for (int rr = 0; rr < 4; ++rr) {
                int row = wave * 16 + quad * 4 + rr;
                int R2 = base + row;
                if (R2 < N)
                    aggu[(size_t)R2 * 64 + nt * 16 + l15] = acc2[nt][rr] + bias;
            }
        }
    }
}

// ===========================================================================
// Scan chain for counting sort (bucket boundaries derived from per-node prefix)
// ===========================================================================
__global__ __launch_bounds__(256) void scan_sums(
    const unsigned* __restrict__ cnt, unsigned* __restrict__ csum)
{
    __shared__ unsigned s[256];
    const int b = blockIdx.x, t = threadIdx.x;
    s[t] = cnt[b * 512 + t] + cnt[b * 512 + 256 + t];
    __syncthreads();
    for (int d = 128; d > 0; d >>= 1) {
        if (t < d) s[t] += s[t + d];
        __syncthreads();
    }
    if (t == 0) csum[b] = s[0];
}

__global__ __launch_bounds__(256) void scan_chunkoff(unsigned* __restrict__ csum, int nch) {
    __shared__ unsigned s[2][256];
    const int t = threadIdx.x;
    if (nch > 256) {
        if (t == 0) {
            unsigned run = 0;
            for (int j = 0; j < nch; ++j) { unsigned v = csum[j]; csum[j] = run; run += v; }
        }
        return;
    }
    unsigned v = (t < nch) ? csum[t] : 0u;
    s[0][t] = v;
    __syncthreads();
    int src = 0;
    for (int d = 1; d < 256; d <<= 1) {
        int dst = src ^ 1;
        s[dst][t] = s[src][t] + (t >= d ? s[src][t - d] : 0u);
        __syncthreads();
        src = dst;
    }
    if (t < nch) csum[t] = s[src][t] - v;   // exclusive
}

// rowp[i] <- global exclusive prefix; bcur[b] <- rowp at 32-node boundaries
__global__ __launch_bounds__(256) void scan_apply(
    const unsigned* __restrict__ cnt, const unsigned* __restrict__ csum,
    unsigned* __restrict__ rowp, unsigned* __restrict__ bcur)
{
    __shared__ unsigned s[2][512];
    const int b = blockIdx.x, t = threadIdx.x;
    const unsigned base = csum[b];
    s[0][t] = cnt[b * 512 + t];
    s[0][t + 256] = cnt[b * 512 + t + 256];
    __syncthreads();
    int src = 0;
    for (int d = 1; d < 512; d <<= 1) {
        int dst = src ^ 1;
        for (int i = t; i < 512; i += 256)
            s[dst][i] = s[src][i] + (i >= d ? s[src][i - d] : 0u);
        __syncthreads();
        src = dst;
    }
    for (int i = t; i < 512; i += 256) {
        unsigned excl = base + s[src][i] - cnt[b * 512 + i];
        const int node = b * 512 + i;
        rowp[node] = excl;
        if ((node & 31) == 0) bcur[node >> 5] = excl;
    }
}

// ===========================================================================
// bplace: scatter entries into 32-node buckets (NOT sorted within bucket).
// Payload packs everything the walk needs: (i0<<1|slot, i1<<5|node_local).
// ~3125 concurrent write streams -> lines fill before eviction (vs 100K).
// ===========================================================================
__global__ __launch_bounds__(256) void bplace_kernel(
    const int* __restrict__ r2, unsigned* __restrict__ bcur,
    int2* __restrict__ sp2, int M2x2)
{
    int i = blockIdx.x * 256 + threadIdx.x;
    const int T = gridDim.x * 256;
    for (; i < M2x2; i += T) {
        const int2 pr = *(const int2*)(r2 + (i & ~1));
        const int slot = i & 1;
        const int n = slot ? pr.y : pr.x;
        unsigned p = atomicAdd(&bcur[n >> 5], 1u);
        sp2[p] = make_int2((pr.x << 1) | slot, (pr.y << 5) | (n & 31));
    }
}

// ===========================================================================
// rel2 fused aggregation over 32-node buckets, LDS f32 accumulators.
// Per entry (wave-parallel, 8-deep load batching): h = relu(P0[i0]+P1[i1]),
// ds_add_f32 into sAcc[slot][node_local][col]. Then per bucket one MFMA
// sweep: agg = cnt1*aggu + sum_s H_s@W2[s] + c_s*b2[s].
// ===========================================================================
__global__ __launch_bounds__(256) void rel2_fused_kernel(
    const bf16* __restrict__ P0, const bf16* __restrict__ P1,
    const int2* __restrict__ sp2,
    const unsigned* __restrict__ rowp, const unsigned* __restrict__ cnt1,
    const float* __restrict__ W2, const float* __restrict__ b2,   // 128x128,128
    float* agg, int N, int numBuckets)
{
    const int AST = 132;                    // padded f32 row stride
    __shared__ float sAcc[2 * 32 * 132];    // ~33.8 KB
    __shared__ float sCnt[2][32];

    const int t = threadIdx.x;
    const int wave = t >> 6, lane = t & 63;
    const int l15 = lane & 15, quad = lane >> 4;

    // W2 fragments: wave owns output cols [wave*16, wave*16+16), both slots
    bf16x8 w2f[2][4];
    #pragma unroll
    for (int s = 0; s < 2; ++s)
        #pragma unroll
        for (int kt = 0; kt < 4; ++kt) {
            bf16x8 f;
            #pragma unroll
            for (int e = 0; e < 8; ++e) {
                int k = kt * 32 + quad * 8 + e;
                f[e] = (bf16)W2[k * 128 + s * 64 + wave * 16 + l15];
            }
            w2f[s][kt] = f;
        }
    const int col = wave * 16 + l15;
    const float b2a = b2[col], b2b = b2[64 + col];

    for (int g = blockIdx.x; g < numBuckets; g += gridDim.x) {
        const int gb = g * 32;
        __syncthreads();   // protect sAcc/sCnt against previous bucket's GEMM

        for (int i = t; i < 2 * 32 * AST; i += 256) sAcc[i] = 0.f;
        if (t < 64) sCnt[t >> 5][t & 31] = 0.f;
        __syncthreads();

        // ---- walk: entries [rowp[gb], rowp[gb+32]) strided across 4 waves ----
        const unsigned e0 = rowp[gb];
        const unsigned end = rowp[gb + 32];
        for (unsigned base = e0 + wave * 64; base < end; base += 256) {
            const int cnt = (int)min(64u, end - base);
            int pk = 0, pb = 0;
            if ((int)lane < cnt) {
                const int2 v = sp2[base + lane];
                pk = v.x; pb = v.y;
            }
            int j = 0;
            for (; j + 8 <= cnt; j += 8) {          // 16 loads in flight
                uint32_t d0v[8], d1v[8]; int av[8], bv[8];
                #pragma unroll
                for (int q = 0; q < 8; ++q) {
                    av[q] = __shfl(pk, j + q);
                    bv[q] = __shfl(pb, j + q);
                    d0v[q] = *(const uint32_t*)(P0 + (size_t)(av[q] >> 1) * 128 + lane * 2);
                    d1v[q] = *(const uint32_t*)(P1 + (size_t)(bv[q] >> 5) * 128 + lane * 2);
                }
                #pragma unroll
                for (int q = 0; q < 8; ++q) {
                    float lo = __uint_as_float(d0v[q] << 16) + __uint_as_float(d1v[q] << 16);
                    float hi = __uint_as_float(d0v[q] & 0xffff0000u) + __uint_as_float(d1v[q] & 0xffff0000u);
                    lo = fmaxf(lo, 0.f); hi = fmaxf(hi, 0.f);
                    float* dst = sAcc + (size_t)(av[q] & 1) * (32 * AST)
                               + (bv[q] & 31) * AST + lane * 2;
                    atomicAdd(dst, lo);
                    atomicAdd(dst + 1, hi);
                    if (lane == 0) atomicAdd(&sCnt[av[q] & 1][bv[q] & 31], 1.f);
                }
            }
            for (; j + 4 <= cnt; j += 4) {
                uint32_t d0v[4], d1v[4]; int av[4], bv[4];
                #pragma unroll
                for (int q = 0; q < 4; ++q) {
                    av[q] = __shfl(pk, j + q);
                    bv[q] = __shfl(pb, j + q);
                    d0v[q] = *(const uint32_t*)(P0 + (size_t)(av[q] >> 1) * 128 + lane * 2);
                    d1v[q] = *(const uint32_t*)(P1 + (size_t)(bv[q] >> 5) * 128 + lane * 2);
                }
                #pragma unroll
                for (int q = 0; q < 4; ++q) {
                    float lo = __uint_as_float(d0v[q] << 16) + __uint_as_float(d1v[q] << 16);
                    float hi = __uint_as_float(d0v[q] & 0xffff0000u) + __uint_as_float(d1v[q] & 0xffff0000u);
                    lo = fmaxf(lo, 0.f); hi = fmaxf(hi, 0.f);
                    float* dst = sAcc + (size_t)(av[q] & 1) * (32 * AST)
                               + (bv[q] & 31) * AST + lane * 2;
                    atomicAdd(dst, lo);
                    atomicAdd(dst + 1, hi);
                    if (lane == 0) atomicAdd(&sCnt[av[q] & 1][bv[q] & 31], 1.f);
                }
            }
            for (; j < cnt; ++j) {
                const int aj = __shfl(pk, j);
                const int bj = __shfl(pb, j);
                const uint32_t d0 = *(const uint32_t*)(P0 + (size_t)(aj >> 1) * 128 + lane * 2);
                const uint32_t d1 = *(const uint32_t*)(P1 + (size_t)(bj >> 5) * 128 + lane * 2);
                float lo = __uint_as_float(d0 << 16) + __uint_as_float(d1 << 16);
                float hi = __uint_as_float(d0 & 0xffff0000u) + __uint_as_float(d1 & 0xffff0000u);
                lo = fmaxf(lo, 0.f); hi = fmaxf(hi, 0.f);
                float* dst = sAcc + (size_t)(aj & 1) * (32 * AST)
                           + (bj & 31) * AST + lane * 2;
                atomicAdd(dst, lo);
                atomicAdd(dst + 1, hi);
                if (lane == 0) atomicAdd(&sCnt[aj & 1][bj & 31], 1.f);
            }
        }
        __syncthreads();

        // ---- GEMM: out[32 nodes][wave's 16 cols] = sum_s H_s @ W2half[s] ----
        f32x4 acc[2];
        #pragma unroll
        for (int mt = 0; mt < 2; ++mt) acc[mt] = (f32x4){0.f, 0.f, 0.f, 0.f};
        #pragma unroll
        for (int s = 0; s < 2; ++s)
            #pragma unroll
            for (int mt = 0; mt < 2; ++mt)
                #pragma unroll
                for (int kt = 0; kt < 4; ++kt) {
                    const float* src = sAcc + (size_t)s * (32 * AST)
                                     + (mt * 16 + l15) * AST + kt * 32 + quad * 8;
                    float4 u0 = *(const float4*)src;
                    float4 u1 = *(const float4*)(src + 4);
                    bf16x8 a = cvt8(u0, u1);
                    acc[mt] = mfma16(a, w2f[s][kt], acc[mt]);
                }
        #pragma unroll
        for (int mt = 0; mt < 2; ++mt)
            #pragma unroll
            for (int rr = 0; rr < 4; ++rr) {
                const int row = mt * 16 + quad * 4 + rr;
                const int n = gb + row;
                if (n < N) {
                    float* ap = agg + (size_t)n * 64 + col;
                    const float au = *ap;                 // unscaled rel1 MLP out
                    *ap = (float)cnt1[n] * au + acc[mt][rr]
                        + sCnt[0][row] * b2a + sCnt[1][row] * b2b;
                }
            }
    }
}

// ===========================================================================
// update: out = relu([emb||agg] @ W1 + b1) @ W2 + b2
// agg aliases out: tile-local read-before-write.
// ===========================================================================
__global__ __launch_bounds__(256) void update_kernel(
    const float* __restrict__ emb, const float* agg,
    const float* __restrict__ W1, const float* __restrict__ b1,  // 128x64, 64
    const float* __restrict__ W2, const float* __restrict__ b2,  // 64x64, 64
    float* out, int N, int numTiles)
{
    __shared__ bf16 sW1t[64 * LD128];
    __shared__ bf16 sW2t[64 * LD64];
    __shared__ bf16 sU[64 * LD128];
    __shared__ bf16 sH[64 * LD64];
    __shared__ float sB1[64], sB2[64];

    const int t = threadIdx.x;
    const int wave = t >> 6, lane = t & 63;
    const int l15 = lane & 15, quad = lane >> 4;
    const int r = t >> 2, p = t & 3;

    for (int i = t; i < 128 * 64; i += 256) {
        int k = i >> 6, n = i & 63;
        sW1t[n * LD128 + k] = (bf16)W1[i];
    }
    for (int i = t; i < 64 * 64; i += 256) {
        int k = i >> 6, n = i & 63;
        sW2t[n * LD64 + k] = (bf16)W2[i];
    }
    if (t < 64) { sB1[t] = b1[t]; sB2[t] = b2[t]; }

    for (int tile = blockIdx.x; tile < numTiles; tile += gridDim.x) {
        __syncthreads();
        const int base = tile * 64;
        {
            const int R = base + r;
            if (R < N) {
                const float* srcp = (p < 2) ? (emb + (size_t)R * 64 + p * 32)
                                            : (agg + (size_t)R * 64 + (p - 2) * 32);
                const float4* src = (const float4*)srcp;
                #pragma unroll
                for (int i = 0; i < 4; ++i)
                    *(bf16x8*)&sU[r * LD128 + p * 32 + i * 8] = cvt8(src[2 * i], src[2 * i + 1]);
            }
        }
        __syncthreads();

        f32x4 acc[4];
        #pragma unroll
        for (int nt = 0; nt < 4; ++nt) acc[nt] = (f32x4){0.f, 0.f, 0.f, 0.f};
        #pragma unroll
        for (int kt = 0; kt < 4; ++kt) {
            bf16x8 a = *(const bf16x8*)&sU[(wave * 16 + l15) * LD128 + kt * 32 + quad * 8];
            #pragma unroll
            for (int nt = 0; nt < 4; ++nt) {
                bf16x8 bfr = *(const bf16x8*)&sW1t[(nt * 16 + l15) * LD128 + kt * 32 + quad * 8];
                acc[nt] = mfma16(a, bfr, acc[nt]);
            }
        }
        #pragma unroll
        for (int nt = 0; nt < 4; ++nt) {
            float bias = sB1[nt * 16 + l15];
            #pragma unroll
            for (int rr = 0; rr < 4; ++rr) {
                float v = acc[nt][rr] + bias;
                v = v > 0.f ? v : 0.f;
                sH[(wave * 16 + quad * 4 + rr) * LD64 + nt * 16 + l15] = (bf16)v;
            }
        }
        __syncthreads();

        f32x4 acc2[4];
        #pragma unroll
        for (int nt = 0; nt < 4; ++nt) acc2[nt] = (f32x4){0.f, 0.f, 0.f, 0.f};
        #pragma unroll
        for (int kt = 0; kt < 2; ++kt) {
            bf16x8 a = *(const bf16x8*)&sH[(wave * 16 + l15) * LD64 + kt * 32 + quad * 8];
            #pragma unroll
            for (int nt = 0; nt < 4; ++nt) {
                bf16x8 bfr = *(const bf16x8*)&sW2t[(nt * 16 + l15) * LD64 + kt * 32 + quad * 8];
                acc2[nt] = mfma16(a, bfr, acc2[nt]);
            }
        }
        #pragma unroll
        for (int nt = 0; nt < 4; ++nt) {
            float bias = sB2[nt * 16 + l15];
            #pragma unroll
            for (int rr = 0; rr < 4; ++rr) {
                int row = wave * 16 + quad * 4 + rr;
                int R = base + row;
                if (R < N)
                    out[(size_t)R * 64 + nt * 16 + l15] = acc2[nt][rr] + bias;
            }
        }
    }
}

// ===========================================================================
// Fallback path (workspace too small): f16 agg + pk atomics (proven).
// ===========================================================================
__global__ __launch_bounds__(256) void rel1_fb_kernel(
    const float* __restrict__ emb, const int* __restrict__ idx,
    const float* __restrict__ W1, const float* __restrict__ b1,
    const float* __restrict__ W2, const float* __restrict__ b2,
    __half* __restrict__ agg, int M, int numTiles)
{
    __shared__ bf16 sW1t[64 * LD64];
    __shared__ bf16 sW2t[64 * LD64];
    __shared__ bf16 sG[64 * LD64];
    __shared__ bf16 sH[64 * LD64];
    __shared__ float sB1[64], sB2[64];
    __shared__ int sIdx[64];

    const int t = threadIdx.x;
    const int wave = t >> 6, lane = t & 63;
    const int l15 = lane & 15, quad = lane >> 4;
    const int r = t >> 2, p = t & 3;

    for (int i = t; i < 64 * 64; i += 256) {
        int k = i >> 6, n = i & 63;
        sW1t[n * LD64 + k] = (bf16)W1[i];
        sW2t[n * LD64 + k] = (bf16)W2[i];
    }
    if (t < 64) { sB1[t] = b1[t]; sB2[t] = b2[t]; }

    for (int tile = blockIdx.x; tile < numTiles; tile += gridDim.x) {
        __syncthreads();
        const int base = tile * 64;
        int id = -1;
        { int R = base + r; if (R < M) id = idx[R]; }
        if (p == 0) sIdx[r] = id;
        if (id >= 0) {
            const float4* src = (const float4*)(emb + (size_t)id * 64 + p * 16);
            float4 v0 = src[0], v1 = src[1], v2 = src[2], v3 = src[3];
            *(bf16x8*)&sG[r * LD64 + p * 16 + 0] = cvt8(v0, v1);
            *(bf16x8*)&sG[r * LD64 + p * 16 + 8] = cvt8(v2, v3);
        }
        __syncthreads();

        f32x4 acc[4];
        #pragma unroll
        for (int nt = 0; nt < 4; ++nt) acc[nt] = (f32x4){0.f, 0.f, 0.f, 0.f};
        #pragma unroll
        for (int kt = 0; kt < 2; ++kt) {
            bf16x8 a = *(const bf16x8*)&sG[(wave * 16 + l15) * LD64 + kt * 32 + quad * 8];
            #pragma unroll
            for (int nt = 0; nt < 4; ++nt) {
                bf16x8 bfr = *(const bf16x8*)&sW1t[(nt * 16 + l15) * LD64 + kt * 32 + quad * 8];
                acc[nt] = mfma16(a, bfr, acc[nt]);
            }
        }
        #pragma unroll
        for (int nt = 0; nt < 4; ++nt) {
            float bias = sB1[nt * 16 + l15];
            #pragma unroll
            for (int rr = 0; rr < 4; ++rr) {
                float v = acc[nt][rr] + bias;
                v = v > 0.f ? v : 0.f;
                sH[(wave * 16 + quad * 4 + rr) * LD64 + nt * 16 + l15] = (bf16)v;
            }
        }
        __syncthreads();

        f32x4 acc2[4];
        #pragma unroll
        for (int nt = 0; nt < 4; ++nt) acc2[nt] = (f32x4){0.f, 0.f, 0.f, 0.f};
        #pragma unroll
        for (int kt = 0; kt < 2; ++kt) {
            bf16x8 a = *(const bf16x8*)&sH[(wave * 16 + l15) * LD64 + kt * 32 + quad * 8];
            #pragma unroll
            for (int nt = 0; nt < 4; ++nt) {
                bf16x8 bfr = *(const bf16x8*)&sW2t[(nt * 16 + l15) * LD64 + kt * 32 + quad * 8];
                acc2[nt] = mfma16(a, bfr, acc2[nt]);
            }
        }
        #pragma unroll
        for (int nt = 0; nt < 4; ++nt) {
            float bias = sB2[nt * 16 + l15];
            const int colb = nt * 16 + (l15 & ~1);
            const int odd = l15 & 1;
            #pragma unroll
            for (int rr = 0; rr < 4; ++rr) {
                float v = acc2[nt][rr] + bias;
                float o = __shfl_xor(v, 1);
                if ((rr >> 1) == odd) {
                    int row = wave * 16 + quad * 4 + rr;
                    int id2 = sIdx[row];
                    if (id2 >= 0)
                        atomic_pk_f16(agg + (size_t)id2 * 64 + colb,
                                      odd ? pack_f16(o, v) : pack_f16(v, o));
                }
            }
        }
    }
}

__global__ __launch_bounds__(256) void rel2_fb_kernel(
    const float* __restrict__ emb, const int* __restrict__ idx,
    const float* __restrict__ W1, const float* __restrict__ b1,
    const float* __restrict__ W2, const float* __restrict__ b2,
    __half* __restrict__ agg, int M, int numTiles)
{
    __shared__ bf16 sG[64 * LD128];
    __shared__ bf16 sH[64 * LD128];
    __shared__ int sIdx[128];

    const int t = threadIdx.x;
    const int wave = t >> 6, lane = t & 63;
    const int l15 = lane & 15, quad = lane >> 4;
    const int r = t >> 2, p = t & 3;

    bf16x8 w1f[2][4], w2f[2][4];
    float bias1[2], bias2[2];
    #pragma unroll
    for (int j = 0; j < 2; ++j) {
        const int n = (wave * 2 + j) * 16 + l15;
        bias1[j] = b1[n];
        bias2[j] = b2[n];
        #pragma unroll
        for (int kt = 0; kt < 4; ++kt) {
            bf16x8 f1, f2;
            #pragma unroll
            for (int e = 0; e < 8; ++e) {
                int k = kt * 32 + quad * 8 + e;
                f1[e] = (bf16)W1[k * 128 + n];
                f2[e] = (bf16)W2[k * 128 + n];
            }
            w1f[j][kt] = f1;
            w2f[j][kt] = f2;
        }
    }

    for (int tile = blockIdx.x; tile < numTiles; tile += gridDim.x) {
        __syncthreads();
        const int base = tile * 64;
        int i0 = -1, i1 = -1;
        { int R = base + r; if (R < M) { i0 = idx[R * 2]; i1 = idx[R * 2 + 1]; } }
        if (p == 0) { sIdx[r * 2] = i0; sIdx[r * 2 + 1] = i1; }
        {
            int myid = (p < 2) ? i0 : i1;
            if (myid >= 0) {
                const float4* src = (const float4*)(emb + (size_t)myid * 64 + (p & 1) * 32);
                #pragma unroll
                for (int i = 0; i < 4; ++i)
                    *(bf16x8*)&sG[r * LD128 + p * 32 + i * 8] = cvt8(src[2 * i], src[2 * i + 1]);
            }
        }
        __syncthreads();

        f32x4 acc[4][2];
        #pragma unroll
        for (int mt = 0; mt < 4; ++mt)
            #pragma unroll
            for (int j = 0; j < 2; ++j) acc[mt][j] = (f32x4){0.f, 0.f, 0.f, 0.f};
        #pragma unroll
        for (int mt = 0; mt < 4; ++mt) {
            #pragma unroll
            for (int kt = 0; kt < 4; ++kt) {
                bf16x8 a = *(const bf16x8*)&sG[(mt * 16 + l15) * LD128 + kt * 32 + quad * 8];
                #pragma unroll
                for (int j = 0; j < 2; ++j) acc[mt][j] = mfma16(a, w1f[j][kt], acc[mt][j]);
            }
        }
        #pragma unroll
        for (int mt = 0; mt < 4; ++mt)
            #pragma unroll
            for (int j = 0; j < 2; ++j) {
                #pragma unroll
                for (int rr = 0; rr < 4; ++rr) {
                    float v = acc[mt][j][rr] + bias1[j];
                    v = v > 0.f ? v : 0.f;
                    sH[(mt * 16 + quad * 4 + rr) * LD128 + (wave * 2 + j) * 16 + l15] = (bf16)v;
                }
            }
        __syncthreads();

        f32x4 acc2[4][2];
        #pragma unroll
        for (int mt = 0; mt < 4; ++mt)
            #pragma unroll
            for (int j = 0; j < 2; ++j) acc2[mt][j] = (f32x4){0.f, 0.f, 0.f, 0.f};
        #pragma unroll
        for (int mt = 0; mt < 4; ++mt) {
            #pragma unroll
            for (int kt = 0; kt < 4; ++kt) {
                bf16x8 a = *(const bf16x8*)&sH[(mt * 16 + l15) * LD128 + kt * 32 + quad * 8];
                #pragma unroll
                for (int j = 0; j < 2; ++j) acc2[mt][j] = mfma16(a, w2f[j][kt], acc2[mt][j]);
            }
        }
        #pragma unroll
        for (int mt = 0; mt < 4; ++mt) {
            #pragma unroll
            for (int j = 0; j < 2; ++j) {
                const int colb = (wave * 2 + j) * 16 + (l15 & ~1);
                const int sel = colb >> 6;
                const int c = colb & 63;
                const int odd = l15 & 1;
                #pragma unroll
                for (int rr = 0; rr < 4; ++rr) {
                    float v = acc2[mt][j][rr] + bias2[j];
                    float o = __shfl_xor(v, 1);
                    if ((rr >> 1) == odd) {
                        int row = mt * 16 + quad * 4 + rr;
                        int id2 = sIdx[row * 2 + sel];
                        if (id2 >= 0)
                            atomic_pk_f16(agg + (size_t)id2 * 64 + c,
                                          odd ? pack_f16(o, v) : pack_f16(v, o));
                    }
                }
            }
        }
    }
}

__global__ __launch_bounds__(256) void update_fb_kernel(
    const float* __restrict__ emb, const __half* __restrict__ agg,
    const float* __restrict__ W1, const float* __restrict__ b1,
    const float* __restrict__ W2, const float* __restrict__ b2,
    float* __restrict__ out, int N, int numTiles)
{
    __shared__ bf16 sW1t[64 * LD128];
    __shared__ bf16 sW2t[64 * LD64];
    __shared__ bf16 sU[64 * LD128];
    __shared__ bf16 sH[64 * LD64];
    __shared__ float sB1[64], sB2[64];

    const int t = threadIdx.x;
    const int wave = t >> 6, lane = t & 63;
    const int l15 = lane & 15, quad = lane >> 4;
    const int r = t >> 2, p = t & 3;

    for (int i = t; i < 128 * 64; i += 256) {
        int k = i >> 6, n = i & 63;
        sW1t[n * LD128 + k] = (bf16)W1[i];
    }
    for (int i = t; i < 64 * 64; i += 256) {
        int k = i >> 6, n = i & 63;
        sW2t[n * LD64 + k] = (bf16)W2[i];
    }
    if (t < 64) { sB1[t] = b1[t]; sB2[t] = b2[t]; }

    for (int tile = blockIdx.x; tile < numTiles; tile += gridDim.x) {
        __syncthreads();
        const int base = tile * 64;
        {
            const int R = base + r;
            if (R < N) {
                if (p < 2) {
                    const float4* src = (const float4*)(emb + (size_t)R * 64 + p * 32);
                    #pragma unroll
                    for (int i = 0; i < 4; ++i)
                        *(bf16x8*)&sU[r * LD128 + p * 32 + i * 8] = cvt8(src[2 * i], src[2 * i + 1]);
                } else {
                    const uint4* src = (const uint4*)(agg + (size_t)R * 64 + (p - 2) * 32);
                    #pragma unroll
                    for (int i = 0; i < 4; ++i) {
                        uint4 u = src[i];
                        bf16x8 o;
                        o[0] = (bf16)h2f_lo(u.x); o[1] = (bf16)h2f_hi(u.x);
                        o[2] = (bf16)h2f_lo(u.y); o[3] = (bf16)h2f_hi(u.y);
                        o[4] = (bf16)h2f_lo(u.z); o[5] = (bf16)h2f_hi(u.z);
                        o[6] = (bf16)h2f_lo(u.w); o[7] = (bf16)h2f_hi(u.w);
                        *(bf16x8*)&sU[r * LD128 + p * 32 + i * 8] = o;
                    }
                }
            }
        }
        __syncthreads();

        f32x4 acc[4];
        #pragma unroll
        for (int nt = 0; nt < 4; ++nt) acc[nt] = (f32x4){0.f, 0.f, 0.f, 0.f};
        #pragma unroll
        for (int kt = 0; kt < 4; ++kt) {
            bf16x8 a = *(const bf16x8*)&sU[(wave * 16 + l15) * LD128 + kt * 32 + quad * 8];
            #pragma unroll
            for (int nt = 0; nt < 4; ++nt) {
                bf16x8 bfr = *(const bf16x8*)&sW1t[(nt * 16 + l15) * LD128 + kt * 32 + quad * 8];
                acc[nt] = mfma16(a, bfr, acc[nt]);
            }
        }
        #pragma unroll
        for (int nt = 0; nt < 4; ++nt) {
            float bias = sB1[nt * 16 + l15];
            #pragma unroll
            for (int rr = 0; rr < 4; ++rr) {
                float v = acc[nt][rr] + bias;
                v = v > 0.f ? v : 0.f;
                sH[(wave * 16 + quad * 4 + rr) * LD64 + nt * 16 + l15] = (bf16)v;
            }
        }
        __syncthreads();

        f32x4 acc2[4];
        #pragma unroll
        for (int nt = 0; nt < 4; ++nt) acc2[nt] = (f32x4){0.f, 0.f, 0.f, 0.f};
        #pragma unroll
        for (int kt = 0; kt < 2; ++kt) {
            bf16x8 a = *(const bf16x8*)&sH[(wave * 16 + l15) * LD64 + kt * 32 + quad * 8];
            #pragma unroll
            for (int nt = 0; nt < 4; ++nt) {
                bf16x8 bfr = *(const bf16x8*)&sW2t[(nt * 16 + l15) * LD64 + kt * 32 + quad * 8];
                acc2[nt] = mfma16(a, bfr, acc2[nt]);
            }
        }
        #pragma unroll
        for (int nt = 0; nt < 4; ++nt) {
            float bias = sB2[nt * 16 + l15];
            #pragma unroll
            for (int rr = 0; rr < 4; ++rr) {
                int row = wave * 16 + quad * 4 + rr;
                int R = base + row;
                if (R < N)
                    out[(size_t)R * 64 + nt * 16 + l15] = acc2[nt][rr] + bias;
            }
        }
    }
}

// ===========================================================================
extern "C" void kernel_launch(void* const* d_in, const int* in_sizes, int n_in,
                              void* d_out, int out_size, void* d_ws, size_t ws_size,
                              hipStream_t stream) {
    const float* emb    = (const float*)d_in[0];
    const int*   rel1   = (const int*)d_in[1];
    const int*   rel2   = (const int*)d_in[2];
    const float* m1W1   = (const float*)d_in[3];
    const float* m1b1   = (const float*)d_in[4];
    const float* m1W2   = (const float*)d_in[5];
    const float* m1b2   = (const float*)d_in[6];
    const float* m2W1   = (const float*)d_in[7];
    const float* m2b1   = (const float*)d_in[8];
    const float* m2W2   = (const float*)d_in[9];
    const float* m2b2   = (const float*)d_in[10];
    const float* uW1    = (const float*)d_in[11];
    const float* ub1    = (const float*)d_in[12];
    const float* uW2    = (const float*)d_in[13];
    const float* ub2    = (const float*)d_in[14];

    const int N    = in_sizes[0] / 64;   // 100000
    const int M1   = in_sizes[1];        // 500000
    const int M2x2 = in_sizes[2];        // 2000000
    const int M2   = M2x2 / 2;

    // ---- workspace layout (agg lives in d_out) ----
    const int nch   = (N + 511) / 512;
    const int nbins = nch * 512;
    const int nbuckets = (N + 31) / 32;  // 3125
    char* wsb = (char*)d_ws;
    size_t off = 0;
    auto take = [&](size_t bytes) {
        size_t cur = off;
        off = (off + bytes + 255) & ~(size_t)255;
        return cur;
    };
    bf16*     P0   = (bf16*)    (wsb + take((size_t)N * 128 * sizeof(bf16)));
    bf16*     P1   = (bf16*)    (wsb + take((size_t)N * 128 * sizeof(bf16)));
    unsigned* cnt1 = (unsigned*)(wsb + take((size_t)nbins * 4));
    unsigned* cnt2 = (unsigned*)(wsb + take((size_t)nbins * 4));
    unsigned* rowp = (unsigned*)(wsb + take((size_t)nbins * 4));
    unsigned* csum = (unsigned*)(wsb + take((size_t)(nch + 64) * 4));
    unsigned* bcur = (unsigned*)(wsb + take((size_t)(nbins / 32 + 64) * 4));
    int2*     sp2  = (int2*)    (wsb + take((size_t)M2x2 * 8));

    if (off <= ws_size) {
        float* agg = (float*)d_out;      // unscaled rel1 out, then final agg

        hipMemsetAsync(cnt1, 0, (size_t)((char*)rowp - (char*)cnt1), stream);

        // front: hist (HB blocks) || prep3 (PT blocks)
        const int HB = 256;
        const int PT = (N + 63) / 64;    // 1563
        front_kernel<<<HB + PT, 256, 0, stream>>>(
            rel1, rel2, cnt1, cnt2, M1, M2x2, HB,
            emb, m2W1, m2b1, m1W1, m1b1, m1W2, m1b2,
            P0, P1, agg, N, PT);

        scan_sums<<<nch, 256, 0, stream>>>(cnt2, csum);
        scan_chunkoff<<<1, 256, 0, stream>>>(csum, nch);
        scan_apply<<<nch, 256, 0, stream>>>(cnt2, csum, rowp, bcur);

        const int gp = ((M2x2 + 255) / 256) < 4096 ? ((M2x2 + 255) / 256) : 4096;
        bplace_kernel<<<gp, 256, 0, stream>>>(rel2, bcur, sp2, M2x2);

        rel2_fused_kernel<<<nbuckets, 256, 0, stream>>>(
            P0, P1, sp2, rowp, cnt1, m2W2, m2b2, agg, N, nbuckets);

        update_kernel<<<PT, 256, 0, stream>>>(emb, agg, uW1, ub1, uW2, ub2,
                                              (float*)d_out, N, PT);
    } else {
        // ---- fallback: f16 agg + pk atomics (proven) ----
        __half* aggh = (__half*)d_ws;
        hipMemsetAsync(aggh, 0, (size_t)N * 64 * sizeof(__half), stream);

        const int t1 = (M1 + 63) / 64;
        rel1_fb_kernel<<<t1 < 1024 ? t1 : 1024, 256, 0, stream>>>(
            emb, rel1, m1W1, m1b1, m1W2, m1b2, aggh, M1, t1);
        const int t2 = (M2 + 63) / 64;
        rel2_fb_kernel<<<t2 < 2048 ? t2 : 2048, 256, 0, stream>>>(
            emb, rel2, m2W1, m2b1, m2W2, m2b2, aggh, M2, t2);
        const int tu = (N + 63) / 64;
        update_fb_kernel<<<tu, 256, 0, stream>>>(emb, aggh, uW1, ub1, uW2, ub2,
                                                 (float*)d_out, N, tu);
    }
}

// Round 8
// 593.212 us; speedup vs baseline: 3.1351x; 3.1351x over previous
//
#include <hip/hip_runtime.h>
#include <hip/hip_fp16.h>

typedef __bf16 bf16;
typedef bf16 bf16x8 __attribute__((ext_vector_type(8)));
typedef float f32x4 __attribute__((ext_vector_type(4)));

#define LD64  80   // padded LDS row stride (elems) for 64-wide tiles
#define LD128 144  // padded LDS row stride for 128-wide tiles

static __device__ __forceinline__ f32x4 mfma16(bf16x8 a, bf16x8 b, f32x4 c) {
    return __builtin_amdgcn_mfma_f32_16x16x32_bf16(a, b, c, 0, 0, 0);
}

static __device__ __forceinline__ bf16x8 cvt8(float4 a, float4 b) {
    bf16x8 v;
    v[0] = (bf16)a.x; v[1] = (bf16)a.y; v[2] = (bf16)a.z; v[3] = (bf16)a.w;
    v[4] = (bf16)b.x; v[5] = (bf16)b.y; v[6] = (bf16)b.z; v[7] = (bf16)b.w;
    return v;
}

static __device__ __forceinline__ uint32_t pack_bf16(float lo, float hi) {
    bf16 a = (bf16)lo, b = (bf16)hi;
    uint16_t ua = *(uint16_t*)&a, ub = *(uint16_t*)&b;
    return ((uint32_t)ub << 16) | (uint32_t)ua;
}

// --- helpers for the fallback (f16 agg) path ---
static __device__ __forceinline__ uint32_t pack_f16(float lo, float hi) {
    __half hl = __float2half_rn(lo), hh = __float2half_rn(hi);
    uint16_t a = *(uint16_t*)&hl, b = *(uint16_t*)&hh;
    return ((uint32_t)b << 16) | (uint32_t)a;
}
static __device__ __forceinline__ void atomic_pk_f16(__half* addr, uint32_t v) {
    asm volatile("global_atomic_pk_add_f16 %0, %1, off" :: "v"(addr), "v"(v) : "memory");
}
static __device__ __forceinline__ float h2f_lo(uint32_t u) {
    uint16_t s = (uint16_t)u; __half h = *(__half*)&s; return __half2float(h);
}
static __device__ __forceinline__ float h2f_hi(uint32_t u) {
    uint16_t s = (uint16_t)(u >> 16); __half h = *(__half*)&s; return __half2float(h);
}

// ===========================================================================
// FRONT: blocks [0,HB) = histogram of rel1+rel2 dests.
//        blocks [HB, HB+PT) = prep3: P0/P1 (msg-GEMM1 halves) + unscaled rel1.
// ===========================================================================
__global__ __launch_bounds__(256) void front_kernel(
    const int* __restrict__ r1, const int* __restrict__ r2,
    unsigned* __restrict__ cnt1, unsigned* __restrict__ cnt2,
    int M1, int M2x2, int HB,
    const float* __restrict__ emb,
    const float* __restrict__ mW1, const float* __restrict__ mb1,   // 128x128,128
    const float* __restrict__ r1W1, const float* __restrict__ r1b1, // 64x64,64
    const float* __restrict__ r1W2, const float* __restrict__ r1b2,
    bf16* __restrict__ P0, bf16* __restrict__ P1,
    float* __restrict__ aggu, int N, int PT)
{
    __shared__ bf16 sG[64 * LD64];
    __shared__ bf16 sH[64 * LD64];
    __shared__ bf16 sW1t[64 * LD64];
    __shared__ bf16 sW2t[64 * LD64];
    __shared__ float sB1[64], sB2[64];

    const int t = threadIdx.x;

    if ((int)blockIdx.x < HB) {   // ---- histogram ----
        int i = blockIdx.x * 256 + t;
        const int T = HB * 256;
        const int tot = M1 + M2x2;
        for (; i < tot; i += T) {
            if (i < M1) atomicAdd(&cnt1[r1[i]], 1u);
            else        atomicAdd(&cnt2[r2[i - M1]], 1u);
        }
        return;
    }

    // ---- prep3 ----
    const int bid = blockIdx.x - HB;
    const int G = gridDim.x - HB;
    const int wave = t >> 6, lane = t & 63;
    const int l15 = lane & 15, quad = lane >> 4;
    const int r = t >> 2, p = t & 3;

    for (int i = t; i < 64 * 64; i += 256) {
        int k = i >> 6, n = i & 63;
        sW1t[n * LD64 + k] = (bf16)r1W1[i];
        sW2t[n * LD64 + k] = (bf16)r1W2[i];
    }
    if (t < 64) { sB1[t] = r1b1[t]; sB2[t] = r1b2[t]; }

    bf16x8 wf0[2][2], wf1[2][2];
    float biasv[2];
    #pragma unroll
    for (int j = 0; j < 2; ++j) {
        const int n = (wave * 2 + j) * 16 + l15;
        biasv[j] = mb1[n];
        #pragma unroll
        for (int kt = 0; kt < 2; ++kt) {
            bf16x8 f0, f1;
            #pragma unroll
            for (int e = 0; e < 8; ++e) {
                int k = kt * 32 + quad * 8 + e;
                f0[e] = (bf16)mW1[k * 128 + n];
                f1[e] = (bf16)mW1[(64 + k) * 128 + n];
            }
            wf0[j][kt] = f0;
            wf1[j][kt] = f1;
        }
    }

    for (int tile = bid; tile < PT; tile += G) {
        __syncthreads();
        const int base = tile * 64;
        const int R = base + r;
        if (R < N) {
            const float4* src = (const float4*)(emb + (size_t)R * 64 + p * 16);
            float4 v0 = src[0], v1 = src[1], v2 = src[2], v3 = src[3];
            *(bf16x8*)&sG[r * LD64 + p * 16 + 0] = cvt8(v0, v1);
            *(bf16x8*)&sG[r * LD64 + p * 16 + 8] = cvt8(v2, v3);
        }
        __syncthreads();

        // --- P-part ---
        f32x4 a0[4][2], a1[4][2];
        #pragma unroll
        for (int mt = 0; mt < 4; ++mt)
            #pragma unroll
            for (int j = 0; j < 2; ++j) {
                a0[mt][j] = (f32x4){0.f, 0.f, 0.f, 0.f};
                a1[mt][j] = (f32x4){0.f, 0.f, 0.f, 0.f};
            }
        #pragma unroll
        for (int mt = 0; mt < 4; ++mt)
            #pragma unroll
            for (int kt = 0; kt < 2; ++kt) {
                bf16x8 a = *(const bf16x8*)&sG[(mt * 16 + l15) * LD64 + kt * 32 + quad * 8];
                #pragma unroll
                for (int j = 0; j < 2; ++j) {
                    a0[mt][j] = mfma16(a, wf0[j][kt], a0[mt][j]);
                    a1[mt][j] = mfma16(a, wf1[j][kt], a1[mt][j]);
                }
            }
        #pragma unroll
        for (int mt = 0; mt < 4; ++mt)
            #pragma unroll
            for (int j = 0; j < 2; ++j) {
                const int colb = (wave * 2 + j) * 16 + (l15 & ~1);
                const int odd = l15 & 1;
                #pragma unroll
                for (int rr = 0; rr < 4; ++rr) {
                    float v = a0[mt][j][rr] + biasv[j];
                    float o = __shfl_xor(v, 1);
                    float w = a1[mt][j][rr];
                    float ow = __shfl_xor(w, 1);
                    if ((rr >> 1) == odd) {
                        int node = base + mt * 16 + quad * 4 + rr;
                        if (node < N) {
                            *(uint32_t*)&P0[(size_t)node * 128 + colb] =
                                odd ? pack_bf16(o, v) : pack_bf16(v, o);
                            *(uint32_t*)&P1[(size_t)node * 128 + colb] =
                                odd ? pack_bf16(ow, w) : pack_bf16(w, ow);
                        }
                    }
                }
            }

        // --- rel1 MLP (unscaled) ---
        f32x4 acc[4];
        #pragma unroll
        for (int nt = 0; nt < 4; ++nt) acc[nt] = (f32x4){0.f, 0.f, 0.f, 0.f};
        #pragma unroll
        for (int kt = 0; kt < 2; ++kt) {
            bf16x8 a = *(const bf16x8*)&sG[(wave * 16 + l15) * LD64 + kt * 32 + quad * 8];
            #pragma unroll
            for (int nt = 0; nt < 4; ++nt) {
                bf16x8 bfr = *(const bf16x8*)&sW1t[(nt * 16 + l15) * LD64 + kt * 32 + quad * 8];
                acc[nt] = mfma16(a, bfr, acc[nt]);
            }
        }
        #pragma unroll
        for (int nt = 0; nt < 4; ++nt) {
            float bias = sB1[nt * 16 + l15];
            #pragma unroll
            for (int rr = 0; rr < 4; ++rr) {
                float v = acc[nt][rr] + bias;
                v = v > 0.f ? v : 0.f;
                sH[(wave * 16 + quad * 4 + rr) * LD64 + nt * 16 + l15] = (bf16)v;
            }
        }
        __syncthreads();

        f32x4 acc2[4];
        #pragma unroll
        for (int nt = 0; nt < 4; ++nt) acc2[nt] = (f32x4){0.f, 0.f, 0.f, 0.f};
        #pragma unroll
        for (int kt = 0; kt < 2; ++kt) {
            bf16x8 a = *(const bf16x8*)&sH[(wave * 16 + l15) * LD64 + kt * 32 + quad * 8];
            #pragma unroll
            for (int nt = 0; nt < 4; ++nt) {
                bf16x8 bfr = *(const bf16x8*)&sW2t[(nt * 16 + l15) * LD64 + kt * 32 + quad * 8];
                acc2[nt] = mfma16(a, bfr, acc2[nt]);
            }
        }
        #pragma unroll
        for (int nt = 0; nt < 4; ++nt) {
            float bias = sB2[nt * 16 + l15];
            #pragma unroll
            for (int rr = 0; rr < 4; ++rr) {
                int row = wave * 16 + quad * 4 + rr;
                int R2 = base + row;
                if (R2 < N)
                    aggu[(size_t)R2 * 64 + nt * 16 + l15] = acc2[nt][rr] + bias;
            }
        }
    }
}

// ===========================================================================
// Scan chain
// ===========================================================================
__global__ __launch_bounds__(256) void scan_sums(
    const unsigned* __restrict__ cnt, unsigned* __restrict__ csum)
{
    __shared__ unsigned s[256];
    const int b = blockIdx.x, t = threadIdx.x;
    s[t] = cnt[b * 512 + t] + cnt[b * 512 + 256 + t];
    __syncthreads();
    for (int d = 128; d > 0; d >>= 1) {
        if (t < d) s[t] += s[t + d];
        __syncthreads();
    }
    if (t == 0) csum[b] = s[0];
}

__global__ __launch_bounds__(256) void scan_chunkoff(unsigned* __restrict__ csum, int nch) {
    __shared__ unsigned s[2][256];
    const int t = threadIdx.x;
    if (nch > 256) {
        if (t == 0) {
            unsigned run = 0;
            for (int j = 0; j < nch; ++j) { unsigned v = csum[j]; csum[j] = run; run += v; }
        }
        return;
    }
    unsigned v = (t < nch) ? csum[t] : 0u;
    s[0][t] = v;
    __syncthreads();
    int src = 0;
    for (int d = 1; d < 256; d <<= 1) {
        int dst = src ^ 1;
        s[dst][t] = s[src][t] + (t >= d ? s[src][t - d] : 0u);
        __syncthreads();
        src = dst;
    }
    if (t < nch) csum[t] = s[src][t] - v;   // exclusive
}

// rowp[i] <- prefix; bcur[b] <- prefix at 32-node boundaries; pcur <- prefix copy
__global__ __launch_bounds__(256) void scan_apply(
    const unsigned* __restrict__ cnt, const unsigned* __restrict__ csum,
    unsigned* __restrict__ rowp, unsigned* __restrict__ bcur,
    unsigned* __restrict__ pcur)
{
    __shared__ unsigned s[2][512];
    const int b = blockIdx.x, t = threadIdx.x;
    const unsigned base = csum[b];
    s[0][t] = cnt[b * 512 + t];
    s[0][t + 256] = cnt[b * 512 + t + 256];
    __syncthreads();
    int src = 0;
    for (int d = 1; d < 512; d <<= 1) {
        int dst = src ^ 1;
        for (int i = t; i < 512; i += 256)
            s[dst][i] = s[src][i] + (i >= d ? s[src][i - d] : 0u);
        __syncthreads();
        src = dst;
    }
    for (int i = t; i < 512; i += 256) {
        unsigned excl = base + s[src][i] - cnt[b * 512 + i];
        const int node = b * 512 + i;
        rowp[node] = excl;
        pcur[node] = excl;
        if ((node & 31) == 0) bcur[node >> 5] = excl;
    }
}

// ===========================================================================
// bplace: XCD-partitioned bucket append. Entries are read by 8 block-classes
// (blockIdx&7 ~ XCD under round-robin dispatch) but appended only by the class
// matching bucket&7 -> each bucket's output lines are written by ONE XCD's L2,
// so lines fill before writeback (kills the 8x write amplification).
// Payload: (pk=(i0<<1)|slot, i1).
// ===========================================================================
__global__ __launch_bounds__(256) void bplace_kernel(
    const int* __restrict__ r2, unsigned* __restrict__ bcur,
    int2* __restrict__ tmp, int M2x2, int GRP)
{
    const int cls = blockIdx.x & 7;
    const int grp = blockIdx.x >> 3;
    const int t = threadIdx.x;
    for (int i = grp * 256 + t; i < M2x2; i += GRP * 256) {
        const int2 pr = *(const int2*)(r2 + (i & ~1));
        const int slot = i & 1;
        const int n = slot ? pr.y : pr.x;
        if (((n >> 5) & 7) == cls) {
            unsigned p = atomicAdd(&bcur[n >> 5], 1u);
            tmp[p] = make_int2((pr.x << 1) | slot, pr.y);
        }
    }
}

// ===========================================================================
// bsort: per bucket, sort entries into per-node order via 32 LDS cursors
// seeded from rowp. Reads tmp sequentially, writes within the bucket's
// contiguous ~5KB output window.
// ===========================================================================
__global__ __launch_bounds__(256) void bsort_kernel(
    const int2* __restrict__ tmp, int2* __restrict__ out,
    const unsigned* __restrict__ rowp, int numBuckets)
{
    __shared__ unsigned cur[32];
    const int t = threadIdx.x;
    for (int b = blockIdx.x; b < numBuckets; b += gridDim.x) {
        const int gb = b * 32;
        __syncthreads();                 // protect cur reuse
        if (t < 32) cur[t] = rowp[gb + t];
        __syncthreads();
        const unsigned s = rowp[gb], e = rowp[gb + 32];
        for (unsigned i = s + t; i < e; i += 256) {
            int2 v = tmp[i];
            const int slot = v.x & 1;
            const int n = slot ? v.y : (v.x >> 1);
            unsigned pos = atomicAdd(&cur[n - gb], 1u);
            out[pos] = v;
        }
    }
}

// mid-fallback: direct per-node sorted placement (R6's proven 195us version)
__global__ __launch_bounds__(256) void place_pernode_kernel(
    const int* __restrict__ r2, unsigned* __restrict__ pcur,
    int2* __restrict__ sp2, int M2x2)
{
    int i = blockIdx.x * 256 + threadIdx.x;
    const int T = gridDim.x * 256;
    for (; i < M2x2; i += T) {
        const int2 pr = *(const int2*)(r2 + (i & ~1));
        const int slot = i & 1;
        const int n = slot ? pr.y : pr.x;
        unsigned p = atomicAdd(&pcur[n], 1u);
        sp2[p] = make_int2((pr.x << 1) | slot, pr.y);
    }
}

// ===========================================================================
// rel2 fused aggregation (R6's proven register-walk version).
// Groups of 32 nodes; 4 waves x 8 nodes. Per node: sum h=relu(P0[i0]+P1[i1])
// over its dest-sorted entries (8-deep load batching) in REGISTERS, write
// per-slot sums to LDS, then one MFMA sweep:
//   agg = cnt1*aggu + sum_s H_s@W2[s] + c_s*b2[s].
// ===========================================================================
__global__ __launch_bounds__(256) void rel2_fused_kernel(
    const bf16* __restrict__ P0, const bf16* __restrict__ P1,
    const int2* __restrict__ sp2,
    const unsigned* __restrict__ rowp, const unsigned* __restrict__ cnt1,
    const float* __restrict__ W2, const float* __restrict__ b2,   // 128x128,128
    float* agg, int N, int numGroups)
{
    const int HLD = 136;
    __shared__ bf16 hT[2][32 * 136];
    __shared__ float sCf[2][32];

    const int t = threadIdx.x;
    const int wave = t >> 6, lane = t & 63;
    const int l15 = lane & 15, quad = lane >> 4;

    bf16x8 w2f[2][4];
    #pragma unroll
    for (int s = 0; s < 2; ++s)
        #pragma unroll
        for (int kt = 0; kt < 4; ++kt) {
            bf16x8 f;
            #pragma unroll
            for (int e = 0; e < 8; ++e) {
                int k = kt * 32 + quad * 8 + e;
                f[e] = (bf16)W2[k * 128 + s * 64 + wave * 16 + l15];
            }
            w2f[s][kt] = f;
        }
    const int col = wave * 16 + l15;
    const float b2a = b2[col], b2b = b2[64 + col];

    for (int g = blockIdx.x; g < numGroups; g += gridDim.x) {
        const int gb = g * 32;
        __syncthreads();   // protect hT/sCf against previous group's GEMM

        // ---- walk: wave fills rows [wave*8, wave*8+8) ----
        for (int k = 0; k < 8; ++k) {
            const int n = gb + wave * 8 + k;
            float a0lo = 0.f, a0hi = 0.f, a1lo = 0.f, a1hi = 0.f;
            float c0 = 0.f, c1 = 0.f;
            if (n < N) {
                unsigned e = rowp[n];
                const unsigned end = rowp[n + 1];
                while (e < end) {
                    const int cnt = (int)min(64u, end - e);
                    int pk = 0, pi1 = 0;
                    if ((int)lane < cnt) {
                        const int2 v = sp2[e + lane];
                        pk = v.x; pi1 = v.y;
                    }
                    unsigned long long bm =
                        __ballot(((int)lane < cnt) && (pk & 1));
                    const int n1 = __popcll(bm);
                    c1 += (float)n1;
                    c0 += (float)(cnt - n1);

                    int j = 0;
                    for (; j + 8 <= cnt; j += 8) {     // 16 loads in flight
                        uint32_t d0v[8], d1v[8]; int ajv[8];
                        #pragma unroll
                        for (int q = 0; q < 8; ++q) {
                            const int aj = __shfl(pk, j + q);
                            const int u1 = __shfl(pi1, j + q);
                            ajv[q] = aj;
                            d0v[q] = *(const uint32_t*)(P0 + (size_t)(aj >> 1) * 128 + lane * 2);
                            d1v[q] = *(const uint32_t*)(P1 + (size_t)u1 * 128 + lane * 2);
                        }
                        #pragma unroll
                        for (int q = 0; q < 8; ++q) {
                            float lo = __uint_as_float(d0v[q] << 16) + __uint_as_float(d1v[q] << 16);
                            float hi = __uint_as_float(d0v[q] & 0xffff0000u) + __uint_as_float(d1v[q] & 0xffff0000u);
                            lo = fmaxf(lo, 0.f); hi = fmaxf(hi, 0.f);
                            if (ajv[q] & 1) { a1lo += lo; a1hi += hi; }
                            else            { a0lo += lo; a0hi += hi; }
                        }
                    }
                    for (; j + 4 <= cnt; j += 4) {
                        uint32_t d0v[4], d1v[4]; int ajv[4];
                        #pragma unroll
                        for (int q = 0; q < 4; ++q) {
                            const int aj = __shfl(pk, j + q);
                            const int u1 = __shfl(pi1, j + q);
                            ajv[q] = aj;
                            d0v[q] = *(const uint32_t*)(P0 + (size_t)(aj >> 1) * 128 + lane * 2);
                            d1v[q] = *(const uint32_t*)(P1 + (size_t)u1 * 128 + lane * 2);
                        }
                        #pragma unroll
                        for (int q = 0; q < 4; ++q) {
                            float lo = __uint_as_float(d0v[q] << 16) + __uint_as_float(d1v[q] << 16);
                            float hi = __uint_as_float(d0v[q] & 0xffff0000u) + __uint_as_float(d1v[q] & 0xffff0000u);
                            lo = fmaxf(lo, 0.f); hi = fmaxf(hi, 0.f);
                            if (ajv[q] & 1) { a1lo += lo; a1hi += hi; }
                            else            { a0lo += lo; a0hi += hi; }
                        }
                    }
                    for (; j < cnt; ++j) {
                        const int aj = __shfl(pk, j);
                        const int u1 = __shfl(pi1, j);
                        const uint32_t d0 = *(const uint32_t*)(P0 + (size_t)(aj >> 1) * 128 + lane * 2);
                        const uint32_t d1 = *(const uint32_t*)(P1 + (size_t)u1 * 128 + lane * 2);
                        float lo = __uint_as_float(d0 << 16) + __uint_as_float(d1 << 16);
                        float hi = __uint_as_float(d0 & 0xffff0000u) + __uint_as_float(d1 & 0xffff0000u);
                        lo = fmaxf(lo, 0.f); hi = fmaxf(hi, 0.f);
                        if (aj & 1) { a1lo += lo; a1hi += hi; }
                        else        { a0lo += lo; a0hi += hi; }
                    }
                    e += cnt;
                }
            }
            const int row = wave * 8 + k;
            *(uint32_t*)&hT[0][row * HLD + lane * 2] = pack_bf16(a0lo, a0hi);
            *(uint32_t*)&hT[1][row * HLD + lane * 2] = pack_bf16(a1lo, a1hi);
            if (lane == 0) { sCf[0][row] = c0; sCf[1][row] = c1; }
        }
        __syncthreads();

        // ---- GEMM: out[32 nodes][wave's 16 cols] = sum_s H_s @ W2half[s] ----
        f32x4 acc[2];
        #pragma unroll
        for (int mt = 0; mt < 2; ++mt) acc[mt] = (f32x4){0.f, 0.f, 0.f, 0.f};
        #pragma unroll
        for (int s = 0; s < 2; ++s)
            #pragma unroll
            for (int mt = 0; mt < 2; ++mt)
                #pragma unroll
                for (int kt = 0; kt < 4; ++kt) {
                    bf16x8 a = *(const bf16x8*)&hT[s][(mt * 16 + l15) * HLD + kt * 32 + quad * 8];
                    acc[mt] = mfma16(a, w2f[s][kt], acc[mt]);
                }
        #pragma unroll
        for (int mt = 0; mt < 2; ++mt)
            #pragma unroll
            for (int rr = 0; rr < 4; ++rr) {
                const int row = mt * 16 + quad * 4 + rr;
                const int n = gb + row;
                if (n < N) {
                    float* ap = agg + (size_t)n * 64 + col;
                    const float au = *ap;                 // unscaled rel1 MLP out
                    *ap = (float)cnt1[n] * au + acc[mt][rr]
                        + sCf[0][row] * b2a + sCf[1][row] * b2b;
                }
            }
    }
}

// ===========================================================================
// update: out = relu([emb||agg] @ W1 + b1) @ W2 + b2 (agg aliases out)
// ===========================================================================
__global__ __launch_bounds__(256) void update_kernel(
    const float* __restrict__ emb, const float* agg,
    const float* __restrict__ W1, const float* __restrict__ b1,  // 128x64, 64
    const float* __restrict__ W2, const float* __restrict__ b2,  // 64x64, 64
    float* out, int N, int numTiles)
{
    __shared__ bf16 sW1t[64 * LD128];
    __shared__ bf16 sW2t[64 * LD64];
    __shared__ bf16 sU[64 * LD128];
    __shared__ bf16 sH[64 * LD64];
    __shared__ float sB1[64], sB2[64];

    const int t = threadIdx.x;
    const int wave = t >> 6, lane = t & 63;
    const int l15 = lane & 15, quad = lane >> 4;
    const int r = t >> 2, p = t & 3;

    for (int i = t; i < 128 * 64; i += 256) {
        int k = i >> 6, n = i & 63;
        sW1t[n * LD128 + k] = (bf16)W1[i];
    }
    for (int i = t; i < 64 * 64; i += 256) {
        int k = i >> 6, n = i & 63;
        sW2t[n * LD64 + k] = (bf16)W2[i];
    }
    if (t < 64) { sB1[t] = b1[t]; sB2[t] = b2[t]; }

    for (int tile = blockIdx.x; tile < numTiles; tile += gridDim.x) {
        __syncthreads();
        const int base = tile * 64;
        {
            const int R = base + r;
            if (R < N) {
                const float* srcp = (p < 2) ? (emb + (size_t)R * 64 + p * 32)
                                            : (agg + (size_t)R * 64 + (p - 2) * 32);
                const float4* src = (const float4*)srcp;
                #pragma unroll
                for (int i = 0; i < 4; ++i)
                    *(bf16x8*)&sU[r * LD128 + p * 32 + i * 8] = cvt8(src[2 * i], src[2 * i + 1]);
            }
        }
        __syncthreads();

        f32x4 acc[4];
        #pragma unroll
        for (int nt = 0; nt < 4; ++nt) acc[nt] = (f32x4){0.f, 0.f, 0.f, 0.f};
        #pragma unroll
        for (int kt = 0; kt < 4; ++kt) {
            bf16x8 a = *(const bf16x8*)&sU[(wave * 16 + l15) * LD128 + kt * 32 + quad * 8];
            #pragma unroll
            for (int nt = 0; nt < 4; ++nt) {
                bf16x8 bfr = *(const bf16x8*)&sW1t[(nt * 16 + l15) * LD128 + kt * 32 + quad * 8];
                acc[nt] = mfma16(a, bfr, acc[nt]);
            }
        }
        #pragma unroll
        for (int nt = 0; nt < 4; ++nt) {
            float bias = sB1[nt * 16 + l15];
            #pragma unroll
            for (int rr = 0; rr < 4; ++rr) {
                float v = acc[nt][rr] + bias;
                v = v > 0.f ? v : 0.f;
                sH[(wave * 16 + quad * 4 + rr) * LD64 + nt * 16 + l15] = (bf16)v;
            }
        }
        __syncthreads();

        f32x4 acc2[4];
        #pragma unroll
        for (int nt = 0; nt < 4; ++nt) acc2[nt] = (f32x4){0.f, 0.f, 0.f, 0.f};
        #pragma unroll
        for (int kt = 0; kt < 2; ++kt) {
            bf16x8 a = *(const bf16x8*)&sH[(wave * 16 + l15) * LD64 + kt * 32 + quad * 8];
            #pragma unroll
            for (int nt = 0; nt < 4; ++nt) {
                bf16x8 bfr = *(const bf16x8*)&sW2t[(nt * 16 + l15) * LD64 + kt * 32 + quad * 8];
                acc2[nt] = mfma16(a, bfr, acc2[nt]);
            }
        }
        #pragma unroll
        for (int nt = 0; nt < 4; ++nt) {
            float bias = sB2[nt * 16 + l15];
            #pragma unroll
            for (int rr = 0; rr < 4; ++rr) {
                int row = wave * 16 + quad * 4 + rr;
                int R = base + row;
                if (R < N)
                    out[(size_t)R * 64 + nt * 16 + l15] = acc2[nt][rr] + bias;
            }
        }
    }
}

// ===========================================================================
// Fallback path (workspace too small): f16 agg + pk atomics (proven).
// ===========================================================================
__global__ __launch_bounds__(256) void rel1_fb_kernel(
    const float* __restrict__ emb, const int* __restrict__ idx,
    const float* __restrict__ W1, const float* __restrict__ b1,
    const float* __restrict__ W2, const float* __restrict__ b2,
    __half* __restrict__ agg, int M, int numTiles)
{
    __shared__ bf16 sW1t[64 * LD64];
    __shared__ bf16 sW2t[64 * LD64];
    __shared__ bf16 sG[64 * LD64];
    __shared__ bf16 sH[64 * LD64];
    __shared__ float sB1[64], sB2[64];
    __shared__ int sIdx[64];

    const int t = threadIdx.x;
    const int wave = t >> 6, lane = t & 63;
    const int l15 = lane & 15, quad = lane >> 4;
    const int r = t >> 2, p = t & 3;

    for (int i = t; i < 64 * 64; i += 256) {
        int k = i >> 6, n = i & 63;
        sW1t[n * LD64 + k] = (bf16)W1[i];
        sW2t[n * LD64 + k] = (bf16)W2[i];
    }
    if (t < 64) { sB1[t] = b1[t]; sB2[t] = b2[t]; }

    for (int tile = blockIdx.x; tile < numTiles; tile += gridDim.x) {
        __syncthreads();
        const int base = tile * 64;
        int id = -1;
        { int R = base + r; if (R < M) id = idx[R]; }
        if (p == 0) sIdx[r] = id;
        if (id >= 0) {
            const float4* src = (const float4*)(emb + (size_t)id * 64 + p * 16);
            float4 v0 = src[0], v1 = src[1], v2 = src[2], v3 = src[3];
            *(bf16x8*)&sG[r * LD64 + p * 16 + 0] = cvt8(v0, v1);
            *(bf16x8*)&sG[r * LD64 + p * 16 + 8] = cvt8(v2, v3);
        }
        __syncthreads();

        f32x4 acc[4];
        #pragma unroll
        for (int nt = 0; nt < 4; ++nt) acc[nt] = (f32x4){0.f, 0.f, 0.f, 0.f};
        #pragma unroll
        for (int kt = 0; kt < 2; ++kt) {
            bf16x8 a = *(const bf16x8*)&sG[(wave * 16 + l15) * LD64 + kt * 32 + quad * 8];
            #pragma unroll
            for (int nt = 0; nt < 4; ++nt) {
                bf16x8 bfr = *(const bf16x8*)&sW1t[(nt * 16 + l15) * LD64 + kt * 32 + quad * 8];
                acc[nt] = mfma16(a, bfr, acc[nt]);
            }
        }
        #pragma unroll
        for (int nt = 0; nt < 4; ++nt) {
            float bias = sB1[nt * 16 + l15];
            #pragma unroll
            for (int rr = 0; rr < 4; ++rr) {
                float v = acc[nt][rr] + bias;
                v = v > 0.f ? v : 0.f;
                sH[(wave * 16 + quad * 4 + rr) * LD64 + nt * 16 + l15] = (bf16)v;
            }
        }
        __syncthreads();

        f32x4 acc2[4];
        #pragma unroll
        for (int nt = 0; nt < 4; ++nt) acc2[nt] = (f32x4){0.f, 0.f, 0.f, 0.f};
        #pragma unroll
        for (int kt = 0; kt < 2; ++kt) {
            bf16x8 a = *(const bf16x8*)&sH[(wave * 16 + l15) * LD64 + kt * 32 + quad * 8];
            #pragma unroll
            for (int nt = 0; nt < 4; ++nt) {
                bf16x8 bfr = *(const bf16x8*)&sW2t[(nt * 16 + l15) * LD64 + kt * 32 + quad * 8];
                acc2[nt] = mfma16(a, bfr, acc2[nt]);
            }
        }
        #pragma unroll
        for (int nt = 0; nt < 4; ++nt) {
            float bias = sB2[nt * 16 + l15];
            const int colb = nt * 16 + (l15 & ~1);
            const int odd = l15 & 1;
            #pragma unroll
            for (int rr = 0; rr < 4; ++rr) {
                float v = acc2[nt][rr] + bias;
                float o = __shfl_xor(v, 1);
                if ((rr >> 1) == odd) {
                    int row = wave * 16 + quad * 4 + rr;
                    int id2 = sIdx[row];
                    if (id2 >= 0)
                        atomic_pk_f16(agg + (size_t)id2 * 64 + colb,
                                      odd ? pack_f16(o, v) : pack_f16(v, o));
                }
            }
        }
    }
}

__global__ __launch_bounds__(256) void rel2_fb_kernel(
    const float* __restrict__ emb, const int* __restrict__ idx,
    const float* __restrict__ W1, const float* __restrict__ b1,
    const float* __restrict__ W2, const float* __restrict__ b2,
    __half* __restrict__ agg, int M, int numTiles)
{
    __shared__ bf16 sG[64 * LD128];
    __shared__ bf16 sH[64 * LD128];
    __shared__ int sIdx[128];

    const int t = threadIdx.x;
    const int wave = t >> 6, lane = t & 63;
    const int l15 = lane & 15, quad = lane >> 4;
    const int r = t >> 2, p = t & 3;

    bf16x8 w1f[2][4], w2f[2][4];
    float bias1[2], bias2[2];
    #pragma unroll
    for (int j = 0; j < 2; ++j) {
        const int n = (wave * 2 + j) * 16 + l15;
        bias1[j] = b1[n];
        bias2[j] = b2[n];
        #pragma unroll
        for (int kt = 0; kt < 4; ++kt) {
            bf16x8 f1, f2;
            #pragma unroll
            for (int e = 0; e < 8; ++e) {
                int k = kt * 32 + quad * 8 + e;
                f1[e] = (bf16)W1[k * 128 + n];
                f2[e] = (bf16)W2[k * 128 + n];
            }
            w1f[j][kt] = f1;
            w2f[j][kt] = f2;
        }
    }

    for (int tile = blockIdx.x; tile < numTiles; tile += gridDim.x) {
        __syncthreads();
        const int base = tile * 64;
        int i0 = -1, i1 = -1;
        { int R = base + r; if (R < M) { i0 = idx[R * 2]; i1 = idx[R * 2 + 1]; } }
        if (p == 0) { sIdx[r * 2] = i0; sIdx[r * 2 + 1] = i1; }
        {
            int myid = (p < 2) ? i0 : i1;
            if (myid >= 0) {
                const float4* src = (const float4*)(emb + (size_t)myid * 64 + (p & 1) * 32);
                #pragma unroll
                for (int i = 0; i < 4; ++i)
                    *(bf16x8*)&sG[r * LD128 + p * 32 + i * 8] = cvt8(src[2 * i], src[2 * i + 1]);
            }
        }
        __syncthreads();

        f32x4 acc[4][2];
        #pragma unroll
        for (int mt = 0; mt < 4; ++mt)
            #pragma unroll
            for (int j = 0; j < 2; ++j) acc[mt][j] = (f32x4){0.f, 0.f, 0.f, 0.f};
        #pragma unroll
        for (int mt = 0; mt < 4; ++mt) {
            #pragma unroll
            for (int kt = 0; kt < 4; ++kt) {
                bf16x8 a = *(const bf16x8*)&sG[(mt * 16 + l15) * LD128 + kt * 32 + quad * 8];
                #pragma unroll
                for (int j = 0; j < 2; ++j) acc[mt][j] = mfma16(a, w1f[j][kt], acc[mt][j]);
            }
        }
        #pragma unroll
        for (int mt = 0; mt < 4; ++mt)
            #pragma unroll
            for (int j = 0; j < 2; ++j) {
                #pragma unroll
                for (int rr = 0; rr < 4; ++rr) {
                    float v = acc[mt][j][rr] + bias1[j];
                    v = v > 0.f ? v : 0.f;
                    sH[(mt * 16 + quad * 4 + rr) * LD128 + (wave * 2 + j) * 16 + l15] = (bf16)v;
                }
            }
        __syncthreads();

        f32x4 acc2[4][2];
        #pragma unroll
        for (int mt = 0; mt < 4; ++mt)
            #pragma unroll
            for (int j = 0; j < 2; ++j) acc2[mt][j] = (f32x4){0.f, 0.f, 0.f, 0.f};
        #pragma unroll
        for (int mt = 0; mt < 4; ++mt) {
            #pragma unroll
            for (int kt = 0; kt < 4; ++kt) {
                bf16x8 a = *(const bf16x8*)&sH[(mt * 16 + l15) * LD128 + kt * 32 + quad * 8];
                #pragma unroll
                for (int j = 0; j < 2; ++j) acc2[mt][j] = mfma16(a, w2f[j][kt], acc2[mt][j]);
            }
        }
        #pragma unroll
        for (int mt = 0; mt < 4; ++mt) {
            #pragma unroll
            for (int j = 0; j < 2; ++j) {
                const int colb = (wave * 2 + j) * 16 + (l15 & ~1);
                const int sel = colb >> 6;
                const int c = colb & 63;
                const int odd = l15 & 1;
                #pragma unroll
                for (int rr = 0; rr < 4; ++rr) {
                    float v = acc2[mt][j][rr] + bias2[j];
                    float o = __shfl_xor(v, 1);
                    if ((rr >> 1) == odd) {
                        int row = mt * 16 + quad * 4 + rr;
                        int id2 = sIdx[row * 2 + sel];
                        if (id2 >= 0)
                            atomic_pk_f16(agg + (size_t)id2 * 64 + c,
                                          odd ? pack_f16(o, v) : pack_f16(v, o));
                    }
                }
            }
        }
    }
}

__global__ __launch_bounds__(256) void update_fb_kernel(
    const float* __restrict__ emb, const __half* __restrict__ agg,
    const float* __restrict__ W1, const float* __restrict__ b1,
    const float* __restrict__ W2, const float* __restrict__ b2,
    float* __restrict__ out, int N, int numTiles)
{
    __shared__ bf16 sW1t[64 * LD128];
    __shared__ bf16 sW2t[64 * LD64];
    __shared__ bf16 sU[64 * LD128];
    __shared__ bf16 sH[64 * LD64];
    __shared__ float sB1[64], sB2[64];

    const int t = threadIdx.x;
    const int wave = t >> 6, lane = t & 63;
    const int l15 = lane & 15, quad = lane >> 4;
    const int r = t >> 2, p = t & 3;

    for (int i = t; i < 128 * 64; i += 256) {
        int k = i >> 6, n = i & 63;
        sW1t[n * LD128 + k] = (bf16)W1[i];
    }
    for (int i = t; i < 64 * 64; i += 256) {
        int k = i >> 6, n = i & 63;
        sW2t[n * LD64 + k] = (bf16)W2[i];
    }
    if (t < 64) { sB1[t] = b1[t]; sB2[t] = b2[t]; }

    for (int tile = blockIdx.x; tile < numTiles; tile += gridDim.x) {
        __syncthreads();
        const int base = tile * 64;
        {
            const int R = base + r;
            if (R < N) {
                if (p < 2) {
                    const float4* src = (const float4*)(emb + (size_t)R * 64 + p * 32);
                    #pragma unroll
                    for (int i = 0; i < 4; ++i)
                        *(bf16x8*)&sU[r * LD128 + p * 32 + i * 8] = cvt8(src[2 * i], src[2 * i + 1]);
                } else {
                    const uint4* src = (const uint4*)(agg + (size_t)R * 64 + (p - 2) * 32);
                    #pragma unroll
                    for (int i = 0; i < 4; ++i) {
                        uint4 u = src[i];
                        bf16x8 o;
                        o[0] = (bf16)h2f_lo(u.x); o[1] = (bf16)h2f_hi(u.x);
                        o[2] = (bf16)h2f_lo(u.y); o[3] = (bf16)h2f_hi(u.y);
                        o[4] = (bf16)h2f_lo(u.z); o[5] = (bf16)h2f_hi(u.z);
                        o[6] = (bf16)h2f_lo(u.w); o[7] = (bf16)h2f_hi(u.w);
                        *(bf16x8*)&sU[r * LD128 + p * 32 + i * 8] = o;
                    }
                }
            }
        }
        __syncthreads();

        f32x4 acc[4];
        #pragma unroll
        for (int nt = 0; nt < 4; ++nt) acc[nt] = (f32x4){0.f, 0.f, 0.f, 0.f};
        #pragma unroll
        for (int kt = 0; kt < 4; ++kt) {
            bf16x8 a = *(const bf16x8*)&sU[(wave * 16 + l15) * LD128 + kt * 32 + quad * 8];
            #pragma unroll
            for (int nt = 0; nt < 4; ++nt) {
                bf16x8 bfr = *(const bf16x8*)&sW1t[(nt * 16 + l15) * LD128 + kt * 32 + quad * 8];
                acc[nt] = mfma16(a, bfr, acc[nt]);
            }
        }
        #pragma unroll
        for (int nt = 0; nt < 4; ++nt) {
            float bias = sB1[nt * 16 + l15];
            #pragma unroll
            for (int rr = 0; rr < 4; ++rr) {
                float v = acc[nt][rr] + bias;
                v = v > 0.f ? v : 0.f;
                sH[(wave * 16 + quad * 4 + rr) * LD64 + nt * 16 + l15] = (bf16)v;
            }
        }
        __syncthreads();

        f32x4 acc2[4];
        #pragma unroll
        for (int nt = 0; nt < 4; ++nt) acc2[nt] = (f32x4){0.f, 0.f, 0.f, 0.f};
        #pragma unroll
        for (int kt = 0; kt < 2; ++kt) {
            bf16x8 a = *(const bf16x8*)&sH[(wave * 16 + l15) * LD64 + kt * 32 + quad * 8];
            #pragma unroll
            for (int nt = 0; nt < 4; ++nt) {
                bf16x8 bfr = *(const bf16x8*)&sW2t[(nt * 16 + l15) * LD64 + kt * 32 + quad * 8];
                acc2[nt] = mfma16(a, bfr, acc2[nt]);
            }
        }
        #pragma unroll
        for (int nt = 0; nt < 4; ++nt) {
            float bias = sB2[nt * 16 + l15];
            #pragma unroll
            for (int rr = 0; rr < 4; ++rr) {
                int row = wave * 16 + quad * 4 + rr;
                int R = base + row;
                if (R < N)
                    out[(size_t)R * 64 + nt * 16 + l15] = acc2[nt][rr] + bias;
            }
        }
    }
}

// ===========================================================================
extern "C" void kernel_launch(void* const* d_in, const int* in_sizes, int n_in,
                              void* d_out, int out_size, void* d_ws, size_t ws_size,
                              hipStream_t stream) {
    const float* emb    = (const float*)d_in[0];
    const int*   rel1   = (const int*)d_in[1];
    const int*   rel2   = (const int*)d_in[2];
    const float* m1W1   = (const float*)d_in[3];
    const float* m1b1   = (const float*)d_in[4];
    const float* m1W2   = (const float*)d_in[5];
    const float* m1b2   = (const float*)d_in[6];
    const float* m2W1   = (const float*)d_in[7];
    const float* m2b1   = (const float*)d_in[8];
    const float* m2W2   = (const float*)d_in[9];
    const float* m2b2   = (const float*)d_in[10];
    const float* uW1    = (const float*)d_in[11];
    const float* ub1    = (const float*)d_in[12];
    const float* uW2    = (const float*)d_in[13];
    const float* ub2    = (const float*)d_in[14];

    const int N    = in_sizes[0] / 64;   // 100000
    const int M1   = in_sizes[1];        // 500000
    const int M2x2 = in_sizes[2];        // 2000000
    const int M2   = M2x2 / 2;

    // ---- workspace layout (agg lives in d_out) ----
    const int nch   = (N + 511) / 512;
    const int nbins = nch * 512;
    const int nbuckets = (N + 31) / 32;  // 3125
    char* wsb = (char*)d_ws;
    size_t off = 0;
    auto take = [&](size_t bytes) {
        size_t cur = off;
        off = (off + bytes + 255) & ~(size_t)255;
        return cur;
    };
    bf16*     P0   = (bf16*)    (wsb + take((size_t)N * 128 * sizeof(bf16)));
    bf16*     P1   = (bf16*)    (wsb + take((size_t)N * 128 * sizeof(bf16)));
    unsigned* cnt1 = (unsigned*)(wsb + take((size_t)nbins * 4));
    unsigned* cnt2 = (unsigned*)(wsb + take((size_t)nbins * 4));
    unsigned* rowp = (unsigned*)(wsb + take((size_t)nbins * 4));
    unsigned* csum = (unsigned*)(wsb + take((size_t)(nch + 64) * 4));
    unsigned* bcur = (unsigned*)(wsb + take((size_t)(nbins / 32 + 64) * 4));
    unsigned* pcur = (unsigned*)(wsb + take((size_t)nbins * 4));
    int2*     sp2  = (int2*)    (wsb + take((size_t)M2x2 * 8));
    const size_t offMid = off;
    int2*     tmp  = (int2*)    (wsb + take((size_t)M2x2 * 8));
    const size_t offFull = off;

    const int mode = (offFull <= ws_size) ? 2 : (offMid <= ws_size) ? 1 : 0;

    if (mode >= 1) {
        float* agg = (float*)d_out;      // unscaled rel1 out, then final agg

        hipMemsetAsync(cnt1, 0, (size_t)((char*)rowp - (char*)cnt1), stream);

        // front: hist (HB blocks) || prep3 (PT blocks)
        const int HB = 256;
        const int PT = (N + 63) / 64;    // 1563
        front_kernel<<<HB + PT, 256, 0, stream>>>(
            rel1, rel2, cnt1, cnt2, M1, M2x2, HB,
            emb, m2W1, m2b1, m1W1, m1b1, m1W2, m1b2,
            P0, P1, agg, N, PT);

        scan_sums<<<nch, 256, 0, stream>>>(cnt2, csum);
        scan_chunkoff<<<1, 256, 0, stream>>>(csum, nch);
        scan_apply<<<nch, 256, 0, stream>>>(cnt2, csum, rowp, bcur, pcur);

        if (mode == 2) {
            // XCD-partitioned bucket append + per-bucket node sort
            const int GRP = 256;                 // groups per class; grid = 8*GRP
            bplace_kernel<<<8 * GRP, 256, 0, stream>>>(rel2, bcur, tmp, M2x2, GRP);
            bsort_kernel<<<nbuckets, 256, 0, stream>>>(tmp, sp2, rowp, nbuckets);
        } else {
            // proven direct per-node sorted placement (R6)
            const int gp = ((M2x2 + 255) / 256) < 4096 ? ((M2x2 + 255) / 256) : 4096;
            place_pernode_kernel<<<gp, 256, 0, stream>>>(rel2, pcur, sp2, M2x2);
        }

        const int NG = nbuckets;                 // 32-node groups
        const int gf = NG < 2048 ? NG : 2048;
        rel2_fused_kernel<<<gf, 256, 0, stream>>>(
            P0, P1, sp2, rowp, cnt1, m2W2, m2b2, agg, N, NG);

        update_kernel<<<PT, 256, 0, stream>>>(emb, agg, uW1, ub1, uW2, ub2,
                                              (float*)d_out, N, PT);
    } else {
        // ---- fallback: f16 agg + pk atomics (proven) ----
        __half* aggh = (__half*)d_ws;
        hipMemsetAsync(aggh, 0, (size_t)N * 64 * sizeof(__half), stream);

        const int t1 = (M1 + 63) / 64;
        rel1_fb_kernel<<<t1 < 1024 ? t1 : 1024, 256, 0, stream>>>(
            emb, rel1, m1W1, m1b1, m1W2, m1b2, aggh, M1, t1);
        const int t2 = (M2 + 63) / 64;
        rel2_fb_kernel<<<t2 < 2048 ? t2 : 2048, 256, 0, stream>>>(
            emb, rel2, m2W1, m2b1, m2W2, m2b2, aggh, M2, t2);
        const int tu = (N + 63) / 64;
        update_fb_kernel<<<tu, 256, 0, stream>>>(emb, aggh, uW1, ub1, uW2, ub2,
                                                 (float*)d_out, N, tu);
    }
}

// Round 9
// 431.652 us; speedup vs baseline: 4.3085x; 1.3743x over previous
//
#include <hip/hip_runtime.h>
#include <hip/hip_fp16.h>

typedef __bf16 bf16;
typedef bf16 bf16x8 __attribute__((ext_vector_type(8)));
typedef float f32x4 __attribute__((ext_vector_type(4)));

#define LD64  80   // padded LDS row stride (elems) for 64-wide tiles
#define LD128 144  // padded LDS row stride for 128-wide tiles

static __device__ __forceinline__ f32x4 mfma16(bf16x8 a, bf16x8 b, f32x4 c) {
    return __builtin_amdgcn_mfma_f32_16x16x32_bf16(a, b, c, 0, 0, 0);
}

static __device__ __forceinline__ bf16x8 cvt8(float4 a, float4 b) {
    bf16x8 v;
    v[0] = (bf16)a.x; v[1] = (bf16)a.y; v[2] = (bf16)a.z; v[3] = (bf16)a.w;
    v[4] = (bf16)b.x; v[5] = (bf16)b.y; v[6] = (bf16)b.z; v[7] = (bf16)b.w;
    return v;
}

static __device__ __forceinline__ uint32_t pack_bf16(float lo, float hi) {
    bf16 a = (bf16)lo, b = (bf16)hi;
    uint16_t ua = *(uint16_t*)&a, ub = *(uint16_t*)&b;
    return ((uint32_t)ub << 16) | (uint32_t)ua;
}

// --- helpers for the fallback (f16 agg) path ---
static __device__ __forceinline__ uint32_t pack_f16(float lo, float hi) {
    __half hl = __float2half_rn(lo), hh = __float2half_rn(hi);
    uint16_t a = *(uint16_t*)&hl, b = *(uint16_t*)&hh;
    return ((uint32_t)b << 16) | (uint32_t)a;
}
static __device__ __forceinline__ void atomic_pk_f16(__half* addr, uint32_t v) {
    asm volatile("global_atomic_pk_add_f16 %0, %1, off" :: "v"(addr), "v"(v) : "memory");
}
static __device__ __forceinline__ float h2f_lo(uint32_t u) {
    uint16_t s = (uint16_t)u; __half h = *(__half*)&s; return __half2float(h);
}
static __device__ __forceinline__ float h2f_hi(uint32_t u) {
    uint16_t s = (uint16_t)(u >> 16); __half h = *(__half*)&s; return __half2float(h);
}

// ===========================================================================
// hist_rk: histogram of rel1+rel2 dests; rel2 atomics capture the RETURN value
// as the entry's within-node rank -> the later scatter needs no atomics.
// ===========================================================================
__global__ __launch_bounds__(256) void hist_rk_kernel(
    const int* __restrict__ r1, const int* __restrict__ r2,
    unsigned* __restrict__ cnt1, unsigned* __restrict__ cnt2,
    unsigned short* __restrict__ rk, int M1, int M2x2)
{
    int i = blockIdx.x * 256 + threadIdx.x;
    const int T = gridDim.x * 256;
    const int tot = M1 + M2x2;
    for (; i < tot; i += T) {
        if (i < M1) {
            atomicAdd(&cnt1[r1[i]], 1u);
        } else {
            const int j = i - M1;
            unsigned r = atomicAdd(&cnt2[r2[j]], 1u);
            rk[j] = (unsigned short)r;
        }
    }
}

// ===========================================================================
// Scan chain
// ===========================================================================
__global__ __launch_bounds__(256) void scan_sums(
    const unsigned* __restrict__ cnt, unsigned* __restrict__ csum)
{
    __shared__ unsigned s[256];
    const int b = blockIdx.x, t = threadIdx.x;
    s[t] = cnt[b * 512 + t] + cnt[b * 512 + 256 + t];
    __syncthreads();
    for (int d = 128; d > 0; d >>= 1) {
        if (t < d) s[t] += s[t + d];
        __syncthreads();
    }
    if (t == 0) csum[b] = s[0];
}

__global__ __launch_bounds__(256) void scan_chunkoff(unsigned* __restrict__ csum, int nch) {
    __shared__ unsigned s[2][256];
    const int t = threadIdx.x;
    if (nch > 256) {
        if (t == 0) {
            unsigned run = 0;
            for (int j = 0; j < nch; ++j) { unsigned v = csum[j]; csum[j] = run; run += v; }
        }
        return;
    }
    unsigned v = (t < nch) ? csum[t] : 0u;
    s[0][t] = v;
    __syncthreads();
    int src = 0;
    for (int d = 1; d < 256; d <<= 1) {
        int dst = src ^ 1;
        s[dst][t] = s[src][t] + (t >= d ? s[src][t - d] : 0u);
        __syncthreads();
        src = dst;
    }
    if (t < nch) csum[t] = s[src][t] - v;   // exclusive
}

// rowp[i] <- global exclusive prefix
__global__ __launch_bounds__(256) void scan_apply(
    const unsigned* __restrict__ cnt, const unsigned* __restrict__ csum,
    unsigned* __restrict__ rowp)
{
    __shared__ unsigned s[2][512];
    const int b = blockIdx.x, t = threadIdx.x;
    const unsigned base = csum[b];
    s[0][t] = cnt[b * 512 + t];
    s[0][t + 256] = cnt[b * 512 + t + 256];
    __syncthreads();
    int src = 0;
    for (int d = 1; d < 512; d <<= 1) {
        int dst = src ^ 1;
        for (int i = t; i < 512; i += 256)
            s[dst][i] = s[src][i] + (i >= d ? s[src][i - d] : 0u);
        __syncthreads();
        src = dst;
    }
    for (int i = t; i < 512; i += 256)
        rowp[b * 512 + i] = base + s[src][i] - cnt[b * 512 + i];
}

// ===========================================================================
// MIX: blocks [0,SB) = atomic-free scatter to final dest-sorted positions
//        (pos = rowp[n] + rk[i]); blocks [SB,...) = prep3 (P0/P1 + unscaled
//        rel1 MLP -> aggu). The scatter is latency/write-bound at low
//        utilization; prep3 is MFMA/BW-bound -> they overlap.
// ===========================================================================
__global__ __launch_bounds__(256) void mix_kernel(
    // scatter args
    const int* __restrict__ r2, const unsigned short* __restrict__ rk,
    const unsigned* __restrict__ rowp, int2* __restrict__ sp2,
    int M2x2, int SB,
    // prep args
    const float* __restrict__ emb,
    const float* __restrict__ mW1, const float* __restrict__ mb1,   // 128x128,128
    const float* __restrict__ r1W1, const float* __restrict__ r1b1, // 64x64,64
    const float* __restrict__ r1W2, const float* __restrict__ r1b2,
    bf16* __restrict__ P0, bf16* __restrict__ P1,
    float* __restrict__ aggu, int N, int PT)
{
    __shared__ bf16 sG[64 * LD64];
    __shared__ bf16 sH[64 * LD64];
    __shared__ bf16 sW1t[64 * LD64];
    __shared__ bf16 sW2t[64 * LD64];
    __shared__ float sB1[64], sB2[64];

    const int t = threadIdx.x;

    if ((int)blockIdx.x < SB) {   // ---- atomic-free scatter ----
        const int T = SB * 256;
        for (int i = blockIdx.x * 256 + t; i < M2x2; i += T) {
            const int2 pr = *(const int2*)(r2 + (i & ~1));
            const int slot = i & 1;
            const int n = slot ? pr.y : pr.x;
            const unsigned pos = rowp[n] + (unsigned)rk[i];
            sp2[pos] = make_int2((pr.x << 1) | slot, pr.y);
        }
        return;
    }

    // ---- prep3 + rel1 ----
    const int bid = blockIdx.x - SB;
    const int G = gridDim.x - SB;
    const int wave = t >> 6, lane = t & 63;
    const int l15 = lane & 15, quad = lane >> 4;
    const int r = t >> 2, p = t & 3;

    for (int i = t; i < 64 * 64; i += 256) {
        int k = i >> 6, n = i & 63;
        sW1t[n * LD64 + k] = (bf16)r1W1[i];
        sW2t[n * LD64 + k] = (bf16)r1W2[i];
    }
    if (t < 64) { sB1[t] = r1b1[t]; sB2[t] = r1b2[t]; }

    bf16x8 wf0[2][2], wf1[2][2];
    float biasv[2];
    #pragma unroll
    for (int j = 0; j < 2; ++j) {
        const int n = (wave * 2 + j) * 16 + l15;
        biasv[j] = mb1[n];
        #pragma unroll
        for (int kt = 0; kt < 2; ++kt) {
            bf16x8 f0, f1;
            #pragma unroll
            for (int e = 0; e < 8; ++e) {
                int k = kt * 32 + quad * 8 + e;
                f0[e] = (bf16)mW1[k * 128 + n];
                f1[e] = (bf16)mW1[(64 + k) * 128 + n];
            }
            wf0[j][kt] = f0;
            wf1[j][kt] = f1;
        }
    }

    for (int tile = bid; tile < PT; tile += G) {
        __syncthreads();
        const int base = tile * 64;
        const int R = base + r;
        if (R < N) {
            const float4* src = (const float4*)(emb + (size_t)R * 64 + p * 16);
            float4 v0 = src[0], v1 = src[1], v2 = src[2], v3 = src[3];
            *(bf16x8*)&sG[r * LD64 + p * 16 + 0] = cvt8(v0, v1);
            *(bf16x8*)&sG[r * LD64 + p * 16 + 8] = cvt8(v2, v3);
        }
        __syncthreads();

        // --- P-part ---
        f32x4 a0[4][2], a1[4][2];
        #pragma unroll
        for (int mt = 0; mt < 4; ++mt)
            #pragma unroll
            for (int j = 0; j < 2; ++j) {
                a0[mt][j] = (f32x4){0.f, 0.f, 0.f, 0.f};
                a1[mt][j] = (f32x4){0.f, 0.f, 0.f, 0.f};
            }
        #pragma unroll
        for (int mt = 0; mt < 4; ++mt)
            #pragma unroll
            for (int kt = 0; kt < 2; ++kt) {
                bf16x8 a = *(const bf16x8*)&sG[(mt * 16 + l15) * LD64 + kt * 32 + quad * 8];
                #pragma unroll
                for (int j = 0; j < 2; ++j) {
                    a0[mt][j] = mfma16(a, wf0[j][kt], a0[mt][j]);
                    a1[mt][j] = mfma16(a, wf1[j][kt], a1[mt][j]);
                }
            }
        #pragma unroll
        for (int mt = 0; mt < 4; ++mt)
            #pragma unroll
            for (int j = 0; j < 2; ++j) {
                const int colb = (wave * 2 + j) * 16 + (l15 & ~1);
                const int odd = l15 & 1;
                #pragma unroll
                for (int rr = 0; rr < 4; ++rr) {
                    float v = a0[mt][j][rr] + biasv[j];
                    float o = __shfl_xor(v, 1);
                    float w = a1[mt][j][rr];
                    float ow = __shfl_xor(w, 1);
                    if ((rr >> 1) == odd) {
                        int node = base + mt * 16 + quad * 4 + rr;
                        if (node < N) {
                            *(uint32_t*)&P0[(size_t)node * 128 + colb] =
                                odd ? pack_bf16(o, v) : pack_bf16(v, o);
                            *(uint32_t*)&P1[(size_t)node * 128 + colb] =
                                odd ? pack_bf16(ow, w) : pack_bf16(w, ow);
                        }
                    }
                }
            }

        // --- rel1 MLP (unscaled) ---
        f32x4 acc[4];
        #pragma unroll
        for (int nt = 0; nt < 4; ++nt) acc[nt] = (f32x4){0.f, 0.f, 0.f, 0.f};
        #pragma unroll
        for (int kt = 0; kt < 2; ++kt) {
            bf16x8 a = *(const bf16x8*)&sG[(wave * 16 + l15) * LD64 + kt * 32 + quad * 8];
            #pragma unroll
            for (int nt = 0; nt < 4; ++nt) {
                bf16x8 bfr = *(const bf16x8*)&sW1t[(nt * 16 + l15) * LD64 + kt * 32 + quad * 8];
                acc[nt] = mfma16(a, bfr, acc[nt]);
            }
        }
        #pragma unroll
        for (int nt = 0; nt < 4; ++nt) {
            float bias = sB1[nt * 16 + l15];
            #pragma unroll
            for (int rr = 0; rr < 4; ++rr) {
                float v = acc[nt][rr] + bias;
                v = v > 0.f ? v : 0.f;
                sH[(wave * 16 + quad * 4 + rr) * LD64 + nt * 16 + l15] = (bf16)v;
            }
        }
        __syncthreads();

        f32x4 acc2[4];
        #pragma unroll
        for (int nt = 0; nt < 4; ++nt) acc2[nt] = (f32x4){0.f, 0.f, 0.f, 0.f};
        #pragma unroll
        for (int kt = 0; kt < 2; ++kt) {
            bf16x8 a = *(const bf16x8*)&sH[(wave * 16 + l15) * LD64 + kt * 32 + quad * 8];
            #pragma unroll
            for (int nt = 0; nt < 4; ++nt) {
                bf16x8 bfr = *(const bf16x8*)&sW2t[(nt * 16 + l15) * LD64 + kt * 32 + quad * 8];
                acc2[nt] = mfma16(a, bfr, acc2[nt]);
            }
        }
        #pragma unroll
        for (int nt = 0; nt < 4; ++nt) {
            float bias = sB2[nt * 16 + l15];
            #pragma unroll
            for (int rr = 0; rr < 4; ++rr) {
                int row = wave * 16 + quad * 4 + rr;
                int R2 = base + row;
                if (R2 < N)
                    aggu[(size_t)R2 * 64 + nt * 16 + l15] = acc2[nt][rr] + bias;
            }
        }
    }
}

// ===========================================================================
// rel2 fused aggregation (R6/R8's proven register-walk version).
// Groups of 32 nodes; 4 waves x 8 nodes. Per node: sum h=relu(P0[i0]+P1[i1])
// over its dest-sorted entries (8-deep load batching) in REGISTERS, write
// per-slot sums to LDS, then one MFMA sweep:
//   agg = cnt1*aggu + sum_s H_s@W2[s] + c_s*b2[s].
// ===========================================================================
__global__ __launch_bounds__(256) void rel2_fused_kernel(
    const bf16* __restrict__ P0, const bf16* __restrict__ P1,
    const int2* __restrict__ sp2,
    const unsigned* __restrict__ rowp, const unsigned* __restrict__ cnt1,
    const float* __restrict__ W2, const float* __restrict__ b2,   // 128x128,128
    float* agg, int N, int numGroups)
{
    const int HLD = 136;
    __shared__ bf16 hT[2][32 * 136];
    __shared__ float sCf[2][32];

    const int t = threadIdx.x;
    const int wave = t >> 6, lane = t & 63;
    const int l15 = lane & 15, quad = lane >> 4;

    bf16x8 w2f[2][4];
    #pragma unroll
    for (int s = 0; s < 2; ++s)
        #pragma unroll
        for (int kt = 0; kt < 4; ++kt) {
            bf16x8 f;
            #pragma unroll
            for (int e = 0; e < 8; ++e) {
                int k = kt * 32 + quad * 8 + e;
                f[e] = (bf16)W2[k * 128 + s * 64 + wave * 16 + l15];
            }
            w2f[s][kt] = f;
        }
    const int col = wave * 16 + l15;
    const float b2a = b2[col], b2b = b2[64 + col];

    for (int g = blockIdx.x; g < numGroups; g += gridDim.x) {
        const int gb = g * 32;
        __syncthreads();   // protect hT/sCf against previous group's GEMM

        // ---- walk: wave fills rows [wave*8, wave*8+8) ----
        for (int k = 0; k < 8; ++k) {
            const int n = gb + wave * 8 + k;
            float a0lo = 0.f, a0hi = 0.f, a1lo = 0.f, a1hi = 0.f;
            float c0 = 0.f, c1 = 0.f;
            if (n < N) {
                unsigned e = rowp[n];
                const unsigned end = rowp[n + 1];
                while (e < end) {
                    const int cnt = (int)min(64u, end - e);
                    int pk = 0, pi1 = 0;
                    if ((int)lane < cnt) {
                        const int2 v = sp2[e + lane];
                        pk = v.x; pi1 = v.y;
                    }
                    unsigned long long bm =
                        __ballot(((int)lane < cnt) && (pk & 1));
                    const int n1 = __popcll(bm);
                    c1 += (float)n1;
                    c0 += (float)(cnt - n1);

                    int j = 0;
                    for (; j + 8 <= cnt; j += 8) {     // 16 loads in flight
                        uint32_t d0v[8], d1v[8]; int ajv[8];
                        #pragma unroll
                        for (int q = 0; q < 8; ++q) {
                            const int aj = __shfl(pk, j + q);
                            const int u1 = __shfl(pi1, j + q);
                            ajv[q] = aj;
                            d0v[q] = *(const uint32_t*)(P0 + (size_t)(aj >> 1) * 128 + lane * 2);
                            d1v[q] = *(const uint32_t*)(P1 + (size_t)u1 * 128 + lane * 2);
                        }
                        #pragma unroll
                        for (int q = 0; q < 8; ++q) {
                            float lo = __uint_as_float(d0v[q] << 16) + __uint_as_float(d1v[q] << 16);
                            float hi = __uint_as_float(d0v[q] & 0xffff0000u) + __uint_as_float(d1v[q] & 0xffff0000u);
                            lo = fmaxf(lo, 0.f); hi = fmaxf(hi, 0.f);
                            if (ajv[q] & 1) { a1lo += lo; a1hi += hi; }
                            else            { a0lo += lo; a0hi += hi; }
                        }
                    }
                    for (; j + 4 <= cnt; j += 4) {
                        uint32_t d0v[4], d1v[4]; int ajv[4];
                        #pragma unroll
                        for (int q = 0; q < 4; ++q) {
                            const int aj = __shfl(pk, j + q);
                            const int u1 = __shfl(pi1, j + q);
                            ajv[q] = aj;
                            d0v[q] = *(const uint32_t*)(P0 + (size_t)(aj >> 1) * 128 + lane * 2);
                            d1v[q] = *(const uint32_t*)(P1 + (size_t)u1 * 128 + lane * 2);
                        }
                        #pragma unroll
                        for (int q = 0; q < 4; ++q) {
                            float lo = __uint_as_float(d0v[q] << 16) + __uint_as_float(d1v[q] << 16);
                            float hi = __uint_as_float(d0v[q] & 0xffff0000u) + __uint_as_float(d1v[q] & 0xffff0000u);
                            lo = fmaxf(lo, 0.f); hi = fmaxf(hi, 0.f);
                            if (ajv[q] & 1) { a1lo += lo; a1hi += hi; }
                            else            { a0lo += lo; a0hi += hi; }
                        }
                    }
                    for (; j < cnt; ++j) {
                        const int aj = __shfl(pk, j);
                        const int u1 = __shfl(pi1, j);
                        const uint32_t d0 = *(const uint32_t*)(P0 + (size_t)(aj >> 1) * 128 + lane * 2);
                        const uint32_t d1 = *(const uint32_t*)(P1 + (size_t)u1 * 128 + lane * 2);
                        float lo = __uint_as_float(d0 << 16) + __uint_as_float(d1 << 16);
                        float hi = __uint_as_float(d0 & 0xffff0000u) + __uint_as_float(d1 & 0xffff0000u);
                        lo = fmaxf(lo, 0.f); hi = fmaxf(hi, 0.f);
                        if (aj & 1) { a1lo += lo; a1hi += hi; }
                        else        { a0lo += lo; a0hi += hi; }
                    }
                    e += cnt;
                }
            }
            const int row = wave * 8 + k;
            *(uint32_t*)&hT[0][row * HLD + lane * 2] = pack_bf16(a0lo, a0hi);
            *(uint32_t*)&hT[1][row * HLD + lane * 2] = pack_bf16(a1lo, a1hi);
            if (lane == 0) { sCf[0][row] = c0; sCf[1][row] = c1; }
        }
        __syncthreads();

        // ---- GEMM: out[32 nodes][wave's 16 cols] = sum_s H_s @ W2half[s] ----
        f32x4 acc[2];
        #pragma unroll
        for (int mt = 0; mt < 2; ++mt) acc[mt] = (f32x4){0.f, 0.f, 0.f, 0.f};
        #pragma unroll
        for (int s = 0; s < 2; ++s)
            #pragma unroll
            for (int mt = 0; mt < 2; ++mt)
                #pragma unroll
                for (int kt = 0; kt < 4; ++kt) {
                    bf16x8 a = *(const bf16x8*)&hT[s][(mt * 16 + l15) * HLD + kt * 32 + quad * 8];
                    acc[mt] = mfma16(a, w2f[s][kt], acc[mt]);
                }
        #pragma unroll
        for (int mt = 0; mt < 2; ++mt)
            #pragma unroll
            for (int rr = 0; rr < 4; ++rr) {
                const int row = mt * 16 + quad * 4 + rr;
                const int n = gb + row;
                if (n < N) {
                    float* ap = agg + (size_t)n * 64 + col;
                    const float au = *ap;                 // unscaled rel1 MLP out
                    *ap = (float)cnt1[n] * au + acc[mt][rr]
                        + sCf[0][row] * b2a + sCf[1][row] * b2b;
                }
            }
    }
}

// ===========================================================================
// update: out = relu([emb||agg] @ W1 + b1) @ W2 + b2 (agg aliases out)
// ===========================================================================
__global__ __launch_bounds__(256) void update_kernel(
    const float* __restrict__ emb, const float* agg,
    const float* __restrict__ W1, const float* __restrict__ b1,  // 128x64, 64
    const float* __restrict__ W2, const float* __restrict__ b2,  // 64x64, 64
    float* out, int N, int numTiles)
{
    __shared__ bf16 sW1t[64 * LD128];
    __shared__ bf16 sW2t[64 * LD64];
    __shared__ bf16 sU[64 * LD128];
    __shared__ bf16 sH[64 * LD64];
    __shared__ float sB1[64], sB2[64];

    const int t = threadIdx.x;
    const int wave = t >> 6, lane = t & 63;
    const int l15 = lane & 15, quad = lane >> 4;
    const int r = t >> 2, p = t & 3;

    for (int i = t; i < 128 * 64; i += 256) {
        int k = i >> 6, n = i & 63;
        sW1t[n * LD128 + k] = (bf16)W1[i];
    }
    for (int i = t; i < 64 * 64; i += 256) {
        int k = i >> 6, n = i & 63;
        sW2t[n * LD64 + k] = (bf16)W2[i];
    }
    if (t < 64) { sB1[t] = b1[t]; sB2[t] = b2[t]; }

    for (int tile = blockIdx.x; tile < numTiles; tile += gridDim.x) {
        __syncthreads();
        const int base = tile * 64;
        {
            const int R = base + r;
            if (R < N) {
                const float* srcp = (p < 2) ? (emb + (size_t)R * 64 + p * 32)
                                            : (agg + (size_t)R * 64 + (p - 2) * 32);
                const float4* src = (const float4*)srcp;
                #pragma unroll
                for (int i = 0; i < 4; ++i)
                    *(bf16x8*)&sU[r * LD128 + p * 32 + i * 8] = cvt8(src[2 * i], src[2 * i + 1]);
            }
        }
        __syncthreads();

        f32x4 acc[4];
        #pragma unroll
        for (int nt = 0; nt < 4; ++nt) acc[nt] = (f32x4){0.f, 0.f, 0.f, 0.f};
        #pragma unroll
        for (int kt = 0; kt < 4; ++kt) {
            bf16x8 a = *(const bf16x8*)&sU[(wave * 16 + l15) * LD128 + kt * 32 + quad * 8];
            #pragma unroll
            for (int nt = 0; nt < 4; ++nt) {
                bf16x8 bfr = *(const bf16x8*)&sW1t[(nt * 16 + l15) * LD128 + kt * 32 + quad * 8];
                acc[nt] = mfma16(a, bfr, acc[nt]);
            }
        }
        #pragma unroll
        for (int nt = 0; nt < 4; ++nt) {
            float bias = sB1[nt * 16 + l15];
            #pragma unroll
            for (int rr = 0; rr < 4; ++rr) {
                float v = acc[nt][rr] + bias;
                v = v > 0.f ? v : 0.f;
                sH[(wave * 16 + quad * 4 + rr) * LD64 + nt * 16 + l15] = (bf16)v;
            }
        }
        __syncthreads();

        f32x4 acc2[4];
        #pragma unroll
        for (int nt = 0; nt < 4; ++nt) acc2[nt] = (f32x4){0.f, 0.f, 0.f, 0.f};
        #pragma unroll
        for (int kt = 0; kt < 2; ++kt) {
            bf16x8 a = *(const bf16x8*)&sH[(wave * 16 + l15) * LD64 + kt * 32 + quad * 8];
            #pragma unroll
            for (int nt = 0; nt < 4; ++nt) {
                bf16x8 bfr = *(const bf16x8*)&sW2t[(nt * 16 + l15) * LD64 + kt * 32 + quad * 8];
                acc2[nt] = mfma16(a, bfr, acc2[nt]);
            }
        }
        #pragma unroll
        for (int nt = 0; nt < 4; ++nt) {
            float bias = sB2[nt * 16 + l15];
            #pragma unroll
            for (int rr = 0; rr < 4; ++rr) {
                int row = wave * 16 + quad * 4 + rr;
                int R = base + row;
                if (R < N)
                    out[(size_t)R * 64 + nt * 16 + l15] = acc2[nt][rr] + bias;
            }
        }
    }
}

// ===========================================================================
// Fallback path (workspace too small): f16 agg + pk atomics (proven).
// ===========================================================================
__global__ __launch_bounds__(256) void rel1_fb_kernel(
    const float* __restrict__ emb, const int* __restrict__ idx,
    const float* __restrict__ W1, const float* __restrict__ b1,
    const float* __restrict__ W2, const float* __restrict__ b2,
    __half* __restrict__ agg, int M, int numTiles)
{
    __shared__ bf16 sW1t[64 * LD64];
    __shared__ bf16 sW2t[64 * LD64];
    __shared__ bf16 sG[64 * LD64];
    __shared__ bf16 sH[64 * LD64];
    __shared__ float sB1[64], sB2[64];
    __shared__ int sIdx[64];

    const int t = threadIdx.x;
    const int wave = t >> 6, lane = t & 63;
    const int l15 = lane & 15, quad = lane >> 4;
    const int r = t >> 2, p = t & 3;

    for (int i = t; i < 64 * 64; i += 256) {
        int k = i >> 6, n = i & 63;
        sW1t[n * LD64 + k] = (bf16)W1[i];
        sW2t[n * LD64 + k] = (bf16)W2[i];
    }
    if (t < 64) { sB1[t] = b1[t]; sB2[t] = b2[t]; }

    for (int tile = blockIdx.x; tile < numTiles; tile += gridDim.x) {
        __syncthreads();
        const int base = tile * 64;
        int id = -1;
        { int R = base + r; if (R < M) id = idx[R]; }
        if (p == 0) sIdx[r] = id;
        if (id >= 0) {
            const float4* src = (const float4*)(emb + (size_t)id * 64 + p * 16);
            float4 v0 = src[0], v1 = src[1], v2 = src[2], v3 = src[3];
            *(bf16x8*)&sG[r * LD64 + p * 16 + 0] = cvt8(v0, v1);
            *(bf16x8*)&sG[r * LD64 + p * 16 + 8] = cvt8(v2, v3);
        }
        __syncthreads();

        f32x4 acc[4];
        #pragma unroll
        for (int nt = 0; nt < 4; ++nt) acc[nt] = (f32x4){0.f, 0.f, 0.f, 0.f};
        #pragma unroll
        for (int kt = 0; kt < 2; ++kt) {
            bf16x8 a = *(const bf16x8*)&sG[(wave * 16 + l15) * LD64 + kt * 32 + quad * 8];
            #pragma unroll
            for (int nt = 0; nt < 4; ++nt) {
                bf16x8 bfr = *(const bf16x8*)&sW1t[(nt * 16 + l15) * LD64 + kt * 32 + quad * 8];
                acc[nt] = mfma16(a, bfr, acc[nt]);
            }
        }
        #pragma unroll
        for (int nt = 0; nt < 4; ++nt) {
            float bias = sB1[nt * 16 + l15];
            #pragma unroll
            for (int rr = 0; rr < 4; ++rr) {
                float v = acc[nt][rr] + bias;
                v = v > 0.f ? v : 0.f;
                sH[(wave * 16 + quad * 4 + rr) * LD64 + nt * 16 + l15] = (bf16)v;
            }
        }
        __syncthreads();

        f32x4 acc2[4];
        #pragma unroll
        for (int nt = 0; nt < 4; ++nt) acc2[nt] = (f32x4){0.f, 0.f, 0.f, 0.f};
        #pragma unroll
        for (int kt = 0; kt < 2; ++kt) {
            bf16x8 a = *(const bf16x8*)&sH[(wave * 16 + l15) * LD64 + kt * 32 + quad * 8];
            #pragma unroll
            for (int nt = 0; nt < 4; ++nt) {
                bf16x8 bfr = *(const bf16x8*)&sW2t[(nt * 16 + l15) * LD64 + kt * 32 + quad * 8];
                acc2[nt] = mfma16(a, bfr, acc2[nt]);
            }
        }
        #pragma unroll
        for (int nt = 0; nt < 4; ++nt) {
            float bias = sB2[nt * 16 + l15];
            const int colb = nt * 16 + (l15 & ~1);
            const int odd = l15 & 1;
            #pragma unroll
            for (int rr = 0; rr < 4; ++rr) {
                float v = acc2[nt][rr] + bias;
                float o = __shfl_xor(v, 1);
                if ((rr >> 1) == odd) {
                    int row = wave * 16 + quad * 4 + rr;
                    int id2 = sIdx[row];
                    if (id2 >= 0)
                        atomic_pk_f16(agg + (size_t)id2 * 64 + colb,
                                      odd ? pack_f16(o, v) : pack_f16(v, o));
                }
            }
        }
    }
}

__global__ __launch_bounds__(256) void rel2_fb_kernel(
    const float* __restrict__ emb, const int* __restrict__ idx,
    const float* __restrict__ W1, const float* __restrict__ b1,
    const float* __restrict__ W2, const float* __restrict__ b2,
    __half* __restrict__ agg, int M, int numTiles)
{
    __shared__ bf16 sG[64 * LD128];
    __shared__ bf16 sH[64 * LD128];
    __shared__ int sIdx[128];

    const int t = threadIdx.x;
    const int wave = t >> 6, lane = t & 63;
    const int l15 = lane & 15, quad = lane >> 4;
    const int r = t >> 2, p = t & 3;

    bf16x8 w1f[2][4], w2f[2][4];
    float bias1[2], bias2[2];
    #pragma unroll
    for (int j = 0; j < 2; ++j) {
        const int n = (wave * 2 + j) * 16 + l15;
        bias1[j] = b1[n];
        bias2[j] = b2[n];
        #pragma unroll
        for (int kt = 0; kt < 4; ++kt) {
            bf16x8 f1, f2;
            #pragma unroll
            for (int e = 0; e < 8; ++e) {
                int k = kt * 32 + quad * 8 + e;
                f1[e] = (bf16)W1[k * 128 + n];
                f2[e] = (bf16)W2[k * 128 + n];
            }
            w1f[j][kt] = f1;
            w2f[j][kt] = f2;
        }
    }

    for (int tile = blockIdx.x; tile < numTiles; tile += gridDim.x) {
        __syncthreads();
        const int base = tile * 64;
        int i0 = -1, i1 = -1;
        { int R = base + r; if (R < M) { i0 = idx[R * 2]; i1 = idx[R * 2 + 1]; } }
        if (p == 0) { sIdx[r * 2] = i0; sIdx[r * 2 + 1] = i1; }
        {
            int myid = (p < 2) ? i0 : i1;
            if (myid >= 0) {
                const float4* src = (const float4*)(emb + (size_t)myid * 64 + (p & 1) * 32);
                #pragma unroll
                for (int i = 0; i < 4; ++i)
                    *(bf16x8*)&sG[r * LD128 + p * 32 + i * 8] = cvt8(src[2 * i], src[2 * i + 1]);
            }
        }
        __syncthreads();

        f32x4 acc[4][2];
        #pragma unroll
        for (int mt = 0; mt < 4; ++mt)
            #pragma unroll
            for (int j = 0; j < 2; ++j) acc[mt][j] = (f32x4){0.f, 0.f, 0.f, 0.f};
        #pragma unroll
        for (int mt = 0; mt < 4; ++mt) {
            #pragma unroll
            for (int kt = 0; kt < 4; ++kt) {
                bf16x8 a = *(const bf16x8*)&sG[(mt * 16 + l15) * LD128 + kt * 32 + quad * 8];
                #pragma unroll
                for (int j = 0; j < 2; ++j) acc[mt][j] = mfma16(a, w1f[j][kt], acc[mt][j]);
            }
        }
        #pragma unroll
        for (int mt = 0; mt < 4; ++mt)
            #pragma unroll
            for (int j = 0; j < 2; ++j) {
                #pragma unroll
                for (int rr = 0; rr < 4; ++rr) {
                    float v = acc[mt][j][rr] + bias1[j];
                    v = v > 0.f ? v : 0.f;
                    sH[(mt * 16 + quad * 4 + rr) * LD128 + (wave * 2 + j) * 16 + l15] = (bf16)v;
                }
            }
        __syncthreads();

        f32x4 acc2[4][2];
        #pragma unroll
        for (int mt = 0; mt < 4; ++mt)
            #pragma unroll
            for (int j = 0; j < 2; ++j) acc2[mt][j] = (f32x4){0.f, 0.f, 0.f, 0.f};
        #pragma unroll
        for (int mt = 0; mt < 4; ++mt) {
            #pragma unroll
            for (int kt = 0; kt < 4; ++kt) {
                bf16x8 a = *(const bf16x8*)&sH[(mt * 16 + l15) * LD128 + kt * 32 + quad * 8];
                #pragma unroll
                for (int j = 0; j < 2; ++j) acc2[mt][j] = mfma16(a, w2f[j][kt], acc2[mt][j]);
            }
        }
        #pragma unroll
        for (int mt = 0; mt < 4; ++mt) {
            #pragma unroll
            for (int j = 0; j < 2; ++j) {
                const int colb = (wave * 2 + j) * 16 + (l15 & ~1);
                const int sel = colb >> 6;
                const int c = colb & 63;
                const int odd = l15 & 1;
                #pragma unroll
                for (int rr = 0; rr < 4; ++rr) {
                    float v = acc2[mt][j][rr] + bias2[j];
                    float o = __shfl_xor(v, 1);
                    if ((rr >> 1) == odd) {
                        int row = mt * 16 + quad * 4 + rr;
                        int id2 = sIdx[row * 2 + sel];
                        if (id2 >= 0)
                            atomic_pk_f16(agg + (size_t)id2 * 64 + c,
                                          odd ? pack_f16(o, v) : pack_f16(v, o));
                    }
                }
            }
        }
    }
}

__global__ __launch_bounds__(256) void update_fb_kernel(
    const float* __restrict__ emb, const __half* __restrict__ agg,
    const float* __restrict__ W1, const float* __restrict__ b1,
    const float* __restrict__ W2, const float* __restrict__ b2,
    float* __restrict__ out, int N, int numTiles)
{
    __shared__ bf16 sW1t[64 * LD128];
    __shared__ bf16 sW2t[64 * LD64];
    __shared__ bf16 sU[64 * LD128];
    __shared__ bf16 sH[64 * LD64];
    __shared__ float sB1[64], sB2[64];

    const int t = threadIdx.x;
    const int wave = t >> 6, lane = t & 63;
    const int l15 = lane & 15, quad = lane >> 4;
    const int r = t >> 2, p = t & 3;

    for (int i = t; i < 128 * 64; i += 256) {
        int k = i >> 6, n = i & 63;
        sW1t[n * LD128 + k] = (bf16)W1[i];
    }
    for (int i = t; i < 64 * 64; i += 256) {
        int k = i >> 6, n = i & 63;
        sW2t[n * LD64 + k] = (bf16)W2[i];
    }
    if (t < 64) { sB1[t] = b1[t]; sB2[t] = b2[t]; }

    for (int tile = blockIdx.x; tile < numTiles; tile += gridDim.x) {
        __syncthreads();
        const int base = tile * 64;
        {
            const int R = base + r;
            if (R < N) {
                if (p < 2) {
                    const float4* src = (const float4*)(emb + (size_t)R * 64 + p * 32);
                    #pragma unroll
                    for (int i = 0; i < 4; ++i)
                        *(bf16x8*)&sU[r * LD128 + p * 32 + i * 8] = cvt8(src[2 * i], src[2 * i + 1]);
                } else {
                    const uint4* src = (const uint4*)(agg + (size_t)R * 64 + (p - 2) * 32);
                    #pragma unroll
                    for (int i = 0; i < 4; ++i) {
                        uint4 u = src[i];
                        bf16x8 o;
                        o[0] = (bf16)h2f_lo(u.x); o[1] = (bf16)h2f_hi(u.x);
                        o[2] = (bf16)h2f_lo(u.y); o[3] = (bf16)h2f_hi(u.y);
                        o[4] = (bf16)h2f_lo(u.z); o[5] = (bf16)h2f_hi(u.z);
                        o[6] = (bf16)h2f_lo(u.w); o[7] = (bf16)h2f_hi(u.w);
                        *(bf16x8*)&sU[r * LD128 + p * 32 + i * 8] = o;
                    }
                }
            }
        }
        __syncthreads();

        f32x4 acc[4];
        #pragma unroll
        for (int nt = 0; nt < 4; ++nt) acc[nt] = (f32x4){0.f, 0.f, 0.f, 0.f};
        #pragma unroll
        for (int kt = 0; kt < 4; ++kt) {
            bf16x8 a = *(const bf16x8*)&sU[(wave * 16 + l15) * LD128 + kt * 32 + quad * 8];
            #pragma unroll
            for (int nt = 0; nt < 4; ++nt) {
                bf16x8 bfr = *(const bf16x8*)&sW1t[(nt * 16 + l15) * LD128 + kt * 32 + quad * 8];
                acc[nt] = mfma16(a, bfr, acc[nt]);
            }
        }
        #pragma unroll
        for (int nt = 0; nt < 4; ++nt) {
            float bias = sB1[nt * 16 + l15];
            #pragma unroll
            for (int rr = 0; rr < 4; ++rr) {
                float v = acc[nt][rr] + bias;
                v = v > 0.f ? v : 0.f;
                sH[(wave * 16 + quad * 4 + rr) * LD64 + nt * 16 + l15] = (bf16)v;
            }
        }
        __syncthreads();

        f32x4 acc2[4];
        #pragma unroll
        for (int nt = 0; nt < 4; ++nt) acc2[nt] = (f32x4){0.f, 0.f, 0.f, 0.f};
        #pragma unroll
        for (int kt = 0; kt < 2; ++kt) {
            bf16x8 a = *(const bf16x8*)&sH[(wave * 16 + l15) * LD64 + kt * 32 + quad * 8];
            #pragma unroll
            for (int nt = 0; nt < 4; ++nt) {
                bf16x8 bfr = *(const bf16x8*)&sW2t[(nt * 16 + l15) * LD64 + kt * 32 + quad * 8];
                acc2[nt] = mfma16(a, bfr, acc2[nt]);
            }
        }
        #pragma unroll
        for (int nt = 0; nt < 4; ++nt) {
            float bias = sB2[nt * 16 + l15];
            #pragma unroll
            for (int rr = 0; rr < 4; ++rr) {
                int row = wave * 16 + quad * 4 + rr;
                int R = base + row;
                if (R < N)
                    out[(size_t)R * 64 + nt * 16 + l15] = acc2[nt][rr] + bias;
            }
        }
    }
}

// ===========================================================================
extern "C" void kernel_launch(void* const* d_in, const int* in_sizes, int n_in,
                              void* d_out, int out_size, void* d_ws, size_t ws_size,
                              hipStream_t stream) {
    const float* emb    = (const float*)d_in[0];
    const int*   rel1   = (const int*)d_in[1];
    const int*   rel2   = (const int*)d_in[2];
    const float* m1W1   = (const float*)d_in[3];
    const float* m1b1   = (const float*)d_in[4];
    const float* m1W2   = (const float*)d_in[5];
    const float* m1b2   = (const float*)d_in[6];
    const float* m2W1   = (const float*)d_in[7];
    const float* m2b1   = (const float*)d_in[8];
    const float* m2W2   = (const float*)d_in[9];
    const float* m2b2   = (const float*)d_in[10];
    const float* uW1    = (const float*)d_in[11];
    const float* ub1    = (const float*)d_in[12];
    const float* uW2    = (const float*)d_in[13];
    const float* ub2    = (const float*)d_in[14];

    const int N    = in_sizes[0] / 64;   // 100000
    const int M1   = in_sizes[1];        // 500000
    const int M2x2 = in_sizes[2];        // 2000000
    const int M2   = M2x2 / 2;

    // ---- workspace layout (agg lives in d_out) ----
    const int nch   = (N + 511) / 512;
    const int nbins = nch * 512;
    const int nbuckets = (N + 31) / 32;  // 3125
    char* wsb = (char*)d_ws;
    size_t off = 0;
    auto take = [&](size_t bytes) {
        size_t cur = off;
        off = (off + bytes + 255) & ~(size_t)255;
        return cur;
    };
    bf16*           P0   = (bf16*)          (wsb + take((size_t)N * 128 * sizeof(bf16)));
    bf16*           P1   = (bf16*)          (wsb + take((size_t)N * 128 * sizeof(bf16)));
    unsigned*       cnt1 = (unsigned*)      (wsb + take((size_t)nbins * 4));
    unsigned*       cnt2 = (unsigned*)      (wsb + take((size_t)nbins * 4));
    unsigned*       rowp = (unsigned*)      (wsb + take((size_t)nbins * 4));
    unsigned*       csum = (unsigned*)      (wsb + take((size_t)(nch + 64) * 4));
    unsigned short* rk   = (unsigned short*)(wsb + take((size_t)M2x2 * 2));
    int2*           sp2  = (int2*)          (wsb + take((size_t)M2x2 * 8));

    if (off <= ws_size) {
        float* agg = (float*)d_out;      // unscaled rel1 out, then final agg

        hipMemsetAsync(cnt1, 0, (size_t)((char*)rowp - (char*)cnt1), stream);

        // 1) histogram with rank capture (rel2 atomics return within-node rank)
        const int gh = 2048;
        hist_rk_kernel<<<gh, 256, 0, stream>>>(rel1, rel2, cnt1, cnt2, rk, M1, M2x2);

        // 2) scan -> rowp
        scan_sums<<<nch, 256, 0, stream>>>(cnt2, csum);
        scan_chunkoff<<<1, 256, 0, stream>>>(csum, nch);
        scan_apply<<<nch, 256, 0, stream>>>(cnt2, csum, rowp);

        // 3) mix: atomic-free scatter (SB blocks) || prep3 + rel1 (PT blocks)
        const int SB = 2048;
        const int PT = (N + 63) / 64;    // 1563
        mix_kernel<<<SB + PT, 256, 0, stream>>>(
            rel2, rk, rowp, sp2, M2x2, SB,
            emb, m2W1, m2b1, m1W1, m1b1, m1W2, m1b2,
            P0, P1, agg, N, PT);

        // 4) fused aggregation (proven register-walk version)
        const int gf = nbuckets < 2048 ? nbuckets : 2048;
        rel2_fused_kernel<<<gf, 256, 0, stream>>>(
            P0, P1, sp2, rowp, cnt1, m2W2, m2b2, agg, N, nbuckets);

        // 5) update
        update_kernel<<<PT, 256, 0, stream>>>(emb, agg, uW1, ub1, uW2, ub2,
                                              (float*)d_out, N, PT);
    } else {
        // ---- fallback: f16 agg + pk atomics (proven) ----
        __half* aggh = (__half*)d_ws;
        hipMemsetAsync(aggh, 0, (size_t)N * 64 * sizeof(__half), stream);

        const int t1 = (M1 + 63) / 64;
        rel1_fb_kernel<<<t1 < 1024 ? t1 : 1024, 256, 0, stream>>>(
            emb, rel1, m1W1, m1b1, m1W2, m1b2, aggh, M1, t1);
        const int t2 = (M2 + 63) / 64;
        rel2_fb_kernel<<<t2 < 2048 ? t2 : 2048, 256, 0, stream>>>(
            emb, rel2, m2W1, m2b1, m2W2, m2b2, aggh, M2, t2);
        const int tu = (N + 63) / 64;
        update_fb_kernel<<<tu, 256, 0, stream>>>(emb, aggh, uW1, ub1, uW2, ub2,
                                                 (float*)d_out, N, tu);
    }
}